// Round 4
// baseline (989.845 us; speedup 1.0000x reference)
//
#include <hip/hip_runtime.h>

// GraphSNN: per-node MLP (13->16->8->8, relu each layer) -> segment_sum over
// dag ids (20k dags) -> per-dag MLP (8->16->8->8, relu each layer) -> sum.
// Output: [num_dags*8] dag_summ ++ [8] global_summ, fp32.
//
// Round 4: same partition/partials structure as round 3 (validated), but the
// fused kernel is rebuilt for issue efficiency:
//  - weights staged once in LDS (432 floats), read as broadcast float4,
//    amortized over IPT=4 nodes processed in parallel per lane
//  - 4 sub-queues keyed by (node & 3): each node's 52B row is loaded with 4
//    aligned dwordx4 (shift Q is compile-time per unrolled sub-queue)
//  - wave-aggregated queue compaction (1 LDS atomic per wave per slot)
//  - acc rows padded to 9 floats: stride 9 -> conflict-free ds_add;
//    un-padded at flush so K_B keeps the validated layout

#define DPP    2880   // dags per partition; acc = 2880*9*4 = 103,680 B
#define NCHUNK 37     // node chunks; 7 partitions * 37 = 259 blocks
#define QC4    2816   // per-sub-queue capacity (exp ~1950, +21 sigma)
#define NTHR   512

// LDS weight layout (float offsets)
#define OW0 0
#define OB0 208
#define OW1 224
#define OB1 352
#define OW2 360
#define OB2 424

// slow path for queue overflow (statistically never taken)
__device__ __forceinline__ void mlp_one_lds(
    const float* __restrict__ inputs, long long n, int drow,
    const float* __restrict__ wl, float* __restrict__ acc)
{
    float x[13];
    #pragma unroll
    for (int k = 0; k < 13; ++k) x[k] = inputs[n * 13 + k];
    float h0[16];
    #pragma unroll
    for (int j = 0; j < 16; ++j) h0[j] = wl[OB0 + j];
    #pragma unroll
    for (int k = 0; k < 13; ++k)
        #pragma unroll
        for (int j = 0; j < 16; ++j) h0[j] = fmaf(x[k], wl[OW0 + k*16 + j], h0[j]);
    #pragma unroll
    for (int j = 0; j < 16; ++j) h0[j] = fmaxf(h0[j], 0.f);
    float h1[8];
    #pragma unroll
    for (int j = 0; j < 8; ++j) h1[j] = wl[OB1 + j];
    #pragma unroll
    for (int k = 0; k < 16; ++k)
        #pragma unroll
        for (int j = 0; j < 8; ++j) h1[j] = fmaf(h0[k], wl[OW1 + k*8 + j], h1[j]);
    #pragma unroll
    for (int j = 0; j < 8; ++j) h1[j] = fmaxf(h1[j], 0.f);
    float h2[8];
    #pragma unroll
    for (int j = 0; j < 8; ++j) h2[j] = wl[OB2 + j];
    #pragma unroll
    for (int k = 0; k < 8; ++k)
        #pragma unroll
        for (int j = 0; j < 8; ++j) h2[j] = fmaf(h1[k], wl[OW2 + k*8 + j], h2[j]);
    float* dst = acc + drow * 9;
    #pragma unroll
    for (int j = 0; j < 8; ++j) atomicAdd(dst + j, fmaxf(h2[j], 0.f));
}

// ---------------------------------------------------------------- K_A
extern "C" __global__ void __launch_bounds__(NTHR) gsnn_fused2(
    const float* __restrict__ inputs,
    const int*   __restrict__ node_to_dag,
    const float* __restrict__ w0, const float* __restrict__ b0,
    const float* __restrict__ w1, const float* __restrict__ b1,
    const float* __restrict__ w2, const float* __restrict__ b2,
    float* __restrict__ partials,      // [npart*NCHUNK][DPP*8]
    int n_nodes, int num_dags, int chunk)
{
    __shared__ float        acc[DPP * 9];       // 103,680 B (stride-9 rows)
    __shared__ unsigned int queue[4][QC4];      // 45,056 B
    __shared__ float        wl[432];            // 1,728 B
    __shared__ int          cnt4[4];

    const int tid = threadIdx.x;
    const int p   = blockIdx.x / NCHUNK;
    const int c   = blockIdx.x % NCHUNK;
    const int lo  = p * DPP;
    const int hi  = min(lo + DPP, num_dags);

    if (tid < 432) {
        float v;
        if      (tid < 208) v = w0[tid];
        else if (tid < 224) v = b0[tid - 208];
        else if (tid < 352) v = w1[tid - 224];
        else if (tid < 360) v = b1[tid - 352];
        else if (tid < 424) v = w2[tid - 360];
        else                v = b2[tid - 424];
        wl[tid] = v;
    }
    for (int i = tid; i < DPP * 9; i += NTHR) acc[i] = 0.f;
    if (tid < 4) cnt4[tid] = 0;
    __syncthreads();

    const int nb   = c * chunk;                 // chunk is a multiple of 4
    const int lane = tid & 63;
    const unsigned long long ltmask = (1ULL << lane) - 1ULL;

    // ---- phase A: scan + 4-way compaction (wave-aggregated atomics) ----
    const int   VC   = chunk >> 2;
    const int4* idx4 = (const int4*)(node_to_dag + nb);
    for (int v = tid; v < VC; v += NTHR) {
        int4 d4;
        const int g = nb + v * 4;
        if (g + 3 < n_nodes) {
            d4 = idx4[v];
        } else {
            d4.x = (g + 0 < n_nodes) ? node_to_dag[g + 0] : -1;
            d4.y = (g + 1 < n_nodes) ? node_to_dag[g + 1] : -1;
            d4.z = (g + 2 < n_nodes) ? node_to_dag[g + 2] : -1;
            d4.w = (g + 3 < n_nodes) ? node_to_dag[g + 3] : -1;
        }
        const int dq[4] = {d4.x, d4.y, d4.z, d4.w};
        #pragma unroll
        for (int q = 0; q < 4; ++q) {
            const int  d    = dq[q];
            const bool pred = (d >= lo) && (d < hi);
            const unsigned long long m = __ballot(pred);
            if (m == 0ULL) continue;
            const int leader = __ffsll((unsigned long long)m) - 1;
            int bpos = 0;
            if (lane == leader) bpos = atomicAdd(&cnt4[q], (int)__popcll(m));
            bpos = __shfl(bpos, leader);
            if (pred) {
                const int pos = bpos + (int)__popcll(m & ltmask);
                const unsigned val =
                    (unsigned)(v * 4 + q) | ((unsigned)(d - lo) << 16);
                if (pos < QC4) queue[q][pos] = val;
                else mlp_one_lds(inputs, (long long)nb + v*4 + q, d - lo, wl, acc);
            }
        }
    }
    __syncthreads();

    // ---- phase B: dense 4-node-per-lane MLP over each sub-queue ----
    const float4* w0v = (const float4*)(wl + OW0);
    const float4* b0v = (const float4*)(wl + OB0);
    const float4* w1v = (const float4*)(wl + OW1);
    const float4* b1v = (const float4*)(wl + OB1);
    const float4* w2v = (const float4*)(wl + OW2);
    const float4* b2v = (const float4*)(wl + OB2);
    const float4* in4 = (const float4*)inputs;

    #pragma unroll
    for (int Q = 0; Q < 4; ++Q) {               // Q == (node & 3), compile-time
        const int total = min(cnt4[Q], QC4);
        for (int base = tid * 4; base < total; base += NTHR * 4) {
            const uint4 e  = *(const uint4*)&queue[Q][base];
            const int   nv = min(total - base, 4);
            unsigned ev[4] = {e.x, e.y, e.z, e.w};
            #pragma unroll
            for (int j = 1; j < 4; ++j) if (j >= nv) ev[j] = ev[0];

            float xb[4][16];
            int   drow[4];
            #pragma unroll
            for (int j = 0; j < 4; ++j) {
                const int nloc = (int)(ev[j] & 0xFFFFu);
                drow[j]        = (int)(ev[j] >> 16);
                const long long n = (long long)nb + nloc;   // n & 3 == Q
                if (Q == 3 || n < (long long)n_nodes - 1) {
                    const long long f4 = (n * 13) >> 2;     // 16B-aligned window
                    const float4 r0 = in4[f4 + 0], r1 = in4[f4 + 1];
                    const float4 r2 = in4[f4 + 2], r3 = in4[f4 + 3];
                    xb[j][ 0]=r0.x; xb[j][ 1]=r0.y; xb[j][ 2]=r0.z; xb[j][ 3]=r0.w;
                    xb[j][ 4]=r1.x; xb[j][ 5]=r1.y; xb[j][ 6]=r1.z; xb[j][ 7]=r1.w;
                    xb[j][ 8]=r2.x; xb[j][ 9]=r2.y; xb[j][10]=r2.z; xb[j][11]=r2.w;
                    xb[j][12]=r3.x; xb[j][13]=r3.y; xb[j][14]=r3.z; xb[j][15]=r3.w;
                } else {
                    #pragma unroll
                    for (int k = 0; k < 16; ++k) xb[j][k] = 0.f;
                    #pragma unroll
                    for (int k = 0; k < 13; ++k)
                        xb[j][Q + k] = inputs[n * 13 + k];
                }
            }

            // layer 0: 13 -> 16 (x[k] = xb[.][Q+k], static index)
            float h0[4][16];
            #pragma unroll
            for (int j4 = 0; j4 < 4; ++j4) {
                const float4 bb = b0v[j4];
                #pragma unroll
                for (int j = 0; j < 4; ++j) {
                    h0[j][j4*4+0] = bb.x; h0[j][j4*4+1] = bb.y;
                    h0[j][j4*4+2] = bb.z; h0[j][j4*4+3] = bb.w;
                }
            }
            #pragma unroll
            for (int k = 0; k < 13; ++k) {
                #pragma unroll
                for (int j4 = 0; j4 < 4; ++j4) {
                    const float4 w = w0v[k*4 + j4];
                    #pragma unroll
                    for (int j = 0; j < 4; ++j) {
                        const float xv = xb[j][Q + k];
                        h0[j][j4*4+0] = fmaf(xv, w.x, h0[j][j4*4+0]);
                        h0[j][j4*4+1] = fmaf(xv, w.y, h0[j][j4*4+1]);
                        h0[j][j4*4+2] = fmaf(xv, w.z, h0[j][j4*4+2]);
                        h0[j][j4*4+3] = fmaf(xv, w.w, h0[j][j4*4+3]);
                    }
                }
            }
            #pragma unroll
            for (int j = 0; j < 4; ++j)
                #pragma unroll
                for (int i = 0; i < 16; ++i) h0[j][i] = fmaxf(h0[j][i], 0.f);

            // layer 1: 16 -> 8
            float h1[4][8];
            #pragma unroll
            for (int j4 = 0; j4 < 2; ++j4) {
                const float4 bb = b1v[j4];
                #pragma unroll
                for (int j = 0; j < 4; ++j) {
                    h1[j][j4*4+0] = bb.x; h1[j][j4*4+1] = bb.y;
                    h1[j][j4*4+2] = bb.z; h1[j][j4*4+3] = bb.w;
                }
            }
            #pragma unroll
            for (int k = 0; k < 16; ++k) {
                #pragma unroll
                for (int j4 = 0; j4 < 2; ++j4) {
                    const float4 w = w1v[k*2 + j4];
                    #pragma unroll
                    for (int j = 0; j < 4; ++j) {
                        const float xv = h0[j][k];
                        h1[j][j4*4+0] = fmaf(xv, w.x, h1[j][j4*4+0]);
                        h1[j][j4*4+1] = fmaf(xv, w.y, h1[j][j4*4+1]);
                        h1[j][j4*4+2] = fmaf(xv, w.z, h1[j][j4*4+2]);
                        h1[j][j4*4+3] = fmaf(xv, w.w, h1[j][j4*4+3]);
                    }
                }
            }
            #pragma unroll
            for (int j = 0; j < 4; ++j)
                #pragma unroll
                for (int i = 0; i < 8; ++i) h1[j][i] = fmaxf(h1[j][i], 0.f);

            // layer 2: 8 -> 8
            float h2[4][8];
            #pragma unroll
            for (int j4 = 0; j4 < 2; ++j4) {
                const float4 bb = b2v[j4];
                #pragma unroll
                for (int j = 0; j < 4; ++j) {
                    h2[j][j4*4+0] = bb.x; h2[j][j4*4+1] = bb.y;
                    h2[j][j4*4+2] = bb.z; h2[j][j4*4+3] = bb.w;
                }
            }
            #pragma unroll
            for (int k = 0; k < 8; ++k) {
                #pragma unroll
                for (int j4 = 0; j4 < 2; ++j4) {
                    const float4 w = w2v[k*2 + j4];
                    #pragma unroll
                    for (int j = 0; j < 4; ++j) {
                        const float xv = h1[j][k];
                        h2[j][j4*4+0] = fmaf(xv, w.x, h2[j][j4*4+0]);
                        h2[j][j4*4+1] = fmaf(xv, w.y, h2[j][j4*4+1]);
                        h2[j][j4*4+2] = fmaf(xv, w.z, h2[j][j4*4+2]);
                        h2[j][j4*4+3] = fmaf(xv, w.w, h2[j][j4*4+3]);
                    }
                }
            }

            // scatter: stride-9 rows -> conflict-free ds_add
            #pragma unroll
            for (int j = 0; j < 4; ++j) {
                if (j < nv) {
                    float* dst = acc + drow[j] * 9;
                    #pragma unroll
                    for (int jj = 0; jj < 8; ++jj)
                        atomicAdd(dst + jj, fmaxf(h2[j][jj], 0.f));
                }
            }
        }
    }
    __syncthreads();

    // ---- flush: un-pad stride-9 -> dense [DPP*8] (validated K_B layout) ----
    float4* out4 = (float4*)(partials + (size_t)blockIdx.x * (DPP * 8));
    for (int f = tid; f < DPP * 2; f += NTHR) {
        const int row = f >> 1, j0 = (f & 1) << 2;
        const float* a = acc + row * 9 + j0;
        float4 vv; vv.x = a[0]; vv.y = a[1]; vv.z = a[2]; vv.w = a[3];
        out4[f] = vv;
    }
}

// ---------------------------------------------------------------- K_B
// (round-2/3 validated structure; DPP/NCHUNK updated)
extern "C" __global__ void __launch_bounds__(256) gsnn_dag_finish(
    const float* __restrict__ partials,
    const float* __restrict__ w0, const float* __restrict__ b0,
    const float* __restrict__ w1, const float* __restrict__ b1,
    const float* __restrict__ w2, const float* __restrict__ b2,
    float* __restrict__ dag_summ,
    float* __restrict__ global_out,
    int num_dags)
{
    __shared__ float4 w0s[32];   // [8][16] as [k*4 + j4]
    __shared__ float4 b0s[4];
    __shared__ float4 w1s[32];   // [16][8] as [k*2 + j4]
    __shared__ float4 b1s[2];
    __shared__ float4 w2s[16];   // [8][8]  as [k*2 + j4]
    __shared__ float4 b2s[2];
    __shared__ float  gsum_s[8];

    const int tid = threadIdx.x;
    {
        float* p;
        p = (float*)w0s; for (int i = tid; i < 128; i += 256) p[i] = w0[i];
        p = (float*)w1s; for (int i = tid; i < 128; i += 256) p[i] = w1[i];
        p = (float*)w2s; if (tid < 64) p[tid] = w2[tid];
        p = (float*)b0s; if (tid < 16) p[tid] = b0[tid];
        p = (float*)b1s; if (tid < 8)  p[tid] = b1[tid];
        p = (float*)b2s; if (tid < 8)  p[tid] = b2[tid];
    }
    if (tid < 8) gsum_s[tid] = 0.f;
    __syncthreads();

    const int d = blockIdx.x * 256 + tid;

    float h2[8] = {0.f,0.f,0.f,0.f,0.f,0.f,0.f,0.f};
    if (d < num_dags) {
        const int p_  = d / DPP;
        const int loc = d - p_ * DPP;
        float x[8] = {0.f,0.f,0.f,0.f,0.f,0.f,0.f,0.f};
        #pragma unroll 4
        for (int cc = 0; cc < NCHUNK; ++cc) {
            const float4* r = (const float4*)(partials +
                ((size_t)(p_ * NCHUNK + cc) * DPP + loc) * 8);
            const float4 a = r[0], b = r[1];
            x[0]+=a.x; x[1]+=a.y; x[2]+=a.z; x[3]+=a.w;
            x[4]+=b.x; x[5]+=b.y; x[6]+=b.z; x[7]+=b.w;
        }
        {   // write dag_summ row
            float4 o0, o1;
            o0.x=x[0]; o0.y=x[1]; o0.z=x[2]; o0.w=x[3];
            o1.x=x[4]; o1.y=x[5]; o1.z=x[6]; o1.w=x[7];
            float4* out4 = (float4*)(dag_summ + (size_t)d * 8);
            out4[0] = o0; out4[1] = o1;
        }

        float h0[16];
        #pragma unroll
        for (int j4 = 0; j4 < 4; ++j4) {
            const float4 b = b0s[j4];
            h0[j4*4+0]=b.x; h0[j4*4+1]=b.y; h0[j4*4+2]=b.z; h0[j4*4+3]=b.w;
        }
        #pragma unroll
        for (int k = 0; k < 8; ++k) {
            #pragma unroll
            for (int j4 = 0; j4 < 4; ++j4) {
                const float4 w = w0s[k*4 + j4];
                h0[j4*4+0] = fmaf(x[k], w.x, h0[j4*4+0]);
                h0[j4*4+1] = fmaf(x[k], w.y, h0[j4*4+1]);
                h0[j4*4+2] = fmaf(x[k], w.z, h0[j4*4+2]);
                h0[j4*4+3] = fmaf(x[k], w.w, h0[j4*4+3]);
            }
        }
        #pragma unroll
        for (int i = 0; i < 16; ++i) h0[i] = fmaxf(h0[i], 0.f);

        float h1[8];
        #pragma unroll
        for (int j4 = 0; j4 < 2; ++j4) {
            const float4 b = b1s[j4];
            h1[j4*4+0]=b.x; h1[j4*4+1]=b.y; h1[j4*4+2]=b.z; h1[j4*4+3]=b.w;
        }
        #pragma unroll
        for (int k = 0; k < 16; ++k) {
            #pragma unroll
            for (int j4 = 0; j4 < 2; ++j4) {
                const float4 w = w1s[k*2 + j4];
                h1[j4*4+0] = fmaf(h0[k], w.x, h1[j4*4+0]);
                h1[j4*4+1] = fmaf(h0[k], w.y, h1[j4*4+1]);
                h1[j4*4+2] = fmaf(h0[k], w.z, h1[j4*4+2]);
                h1[j4*4+3] = fmaf(h0[k], w.w, h1[j4*4+3]);
            }
        }
        #pragma unroll
        for (int i = 0; i < 8; ++i) h1[i] = fmaxf(h1[i], 0.f);

        #pragma unroll
        for (int j4 = 0; j4 < 2; ++j4) {
            const float4 b = b2s[j4];
            h2[j4*4+0]=b.x; h2[j4*4+1]=b.y; h2[j4*4+2]=b.z; h2[j4*4+3]=b.w;
        }
        #pragma unroll
        for (int k = 0; k < 8; ++k) {
            #pragma unroll
            for (int j4 = 0; j4 < 2; ++j4) {
                const float4 w = w2s[k*2 + j4];
                h2[j4*4+0] = fmaf(h1[k], w.x, h2[j4*4+0]);
                h2[j4*4+1] = fmaf(h1[k], w.y, h2[j4*4+1]);
                h2[j4*4+2] = fmaf(h1[k], w.z, h2[j4*4+2]);
                h2[j4*4+3] = fmaf(h1[k], w.w, h2[j4*4+3]);
            }
        }
        #pragma unroll
        for (int i = 0; i < 8; ++i) h2[i] = fmaxf(h2[i], 0.f);
    }

    #pragma unroll
    for (int j = 0; j < 8; ++j) {
        float v = h2[j];
        for (int off = 32; off > 0; off >>= 1) v += __shfl_down(v, off);
        if ((tid & 63) == 0) atomicAdd(&gsum_s[j], v);
    }
    __syncthreads();
    if (tid < 8) atomicAdd(global_out + tid, gsum_s[tid]);
}

// ---------------------------------------------------------------- fallbacks
extern "C" __global__ void __launch_bounds__(256) gsnn_node_atomic(
    const float* __restrict__ inputs,
    const int*   __restrict__ node_to_dag,
    const float* __restrict__ w0, const float* __restrict__ b0,
    const float* __restrict__ w1, const float* __restrict__ b1,
    const float* __restrict__ w2, const float* __restrict__ b2,
    float* __restrict__ dag_out,
    int n_nodes)
{
    const long long i = (long long)blockIdx.x * 256 + threadIdx.x;
    if (i >= n_nodes) return;
    float x[13];
    #pragma unroll
    for (int k = 0; k < 13; ++k) x[k] = inputs[i*13 + k];
    float h0[16];
    #pragma unroll
    for (int j = 0; j < 16; ++j) h0[j] = b0[j];
    #pragma unroll
    for (int k = 0; k < 13; ++k)
        #pragma unroll
        for (int j = 0; j < 16; ++j) h0[j] = fmaf(x[k], w0[k*16+j], h0[j]);
    #pragma unroll
    for (int j = 0; j < 16; ++j) h0[j] = fmaxf(h0[j], 0.f);
    float h1[8];
    #pragma unroll
    for (int j = 0; j < 8; ++j) h1[j] = b1[j];
    #pragma unroll
    for (int k = 0; k < 16; ++k)
        #pragma unroll
        for (int j = 0; j < 8; ++j) h1[j] = fmaf(h0[k], w1[k*8+j], h1[j]);
    #pragma unroll
    for (int j = 0; j < 8; ++j) h1[j] = fmaxf(h1[j], 0.f);
    float h2[8];
    #pragma unroll
    for (int j = 0; j < 8; ++j) h2[j] = b2[j];
    #pragma unroll
    for (int k = 0; k < 8; ++k)
        #pragma unroll
        for (int j = 0; j < 8; ++j) h2[j] = fmaf(h1[k], w2[k*8+j], h2[j]);
    float* dst = dag_out + (long long)node_to_dag[i] * 8;
    #pragma unroll
    for (int j = 0; j < 8; ++j) atomicAdd(dst + j, fmaxf(h2[j], 0.f));
}

extern "C" __global__ void __launch_bounds__(256) gsnn_dag_plain(
    const float* __restrict__ dag_summ,
    const float* __restrict__ w0, const float* __restrict__ b0,
    const float* __restrict__ w1, const float* __restrict__ b1,
    const float* __restrict__ w2, const float* __restrict__ b2,
    float* __restrict__ global_out,
    int num_dags)
{
    __shared__ float gsum_s[8];
    const int tid = threadIdx.x;
    if (tid < 8) gsum_s[tid] = 0.f;
    __syncthreads();
    const int d = blockIdx.x * 256 + tid;
    float h2[8] = {0.f,0.f,0.f,0.f,0.f,0.f,0.f,0.f};
    if (d < num_dags) {
        float x[8];
        #pragma unroll
        for (int j = 0; j < 8; ++j) x[j] = dag_summ[(size_t)d*8 + j];
        float h0[16];
        #pragma unroll
        for (int j = 0; j < 16; ++j) h0[j] = b0[j];
        #pragma unroll
        for (int k = 0; k < 8; ++k)
            #pragma unroll
            for (int j = 0; j < 16; ++j) h0[j] = fmaf(x[k], w0[k*16+j], h0[j]);
        #pragma unroll
        for (int j = 0; j < 16; ++j) h0[j] = fmaxf(h0[j], 0.f);
        float h1[8];
        #pragma unroll
        for (int j = 0; j < 8; ++j) h1[j] = b1[j];
        #pragma unroll
        for (int k = 0; k < 16; ++k)
            #pragma unroll
            for (int j = 0; j < 8; ++j) h1[j] = fmaf(h0[k], w1[k*8+j], h1[j]);
        #pragma unroll
        for (int j = 0; j < 8; ++j) h1[j] = fmaxf(h1[j], 0.f);
        #pragma unroll
        for (int j = 0; j < 8; ++j) h2[j] = b2[j];
        #pragma unroll
        for (int k = 0; k < 8; ++k)
            #pragma unroll
            for (int j = 0; j < 8; ++j) h2[j] = fmaf(h1[k], w2[k*8+j], h2[j]);
        #pragma unroll
        for (int j = 0; j < 8; ++j) h2[j] = fmaxf(h2[j], 0.f);
    }
    #pragma unroll
    for (int j = 0; j < 8; ++j) {
        float v = h2[j];
        for (int off = 32; off > 0; off >>= 1) v += __shfl_down(v, off);
        if ((tid & 63) == 0) atomicAdd(&gsum_s[j], v);
    }
    __syncthreads();
    if (tid < 8) atomicAdd(global_out + tid, gsum_s[tid]);
}

extern "C" void kernel_launch(void* const* d_in, const int* in_sizes, int n_in,
                              void* d_out, int out_size, void* d_ws, size_t ws_size,
                              hipStream_t stream) {
    const float* inputs      = (const float*)d_in[0];
    const int*   node_to_dag = (const int*)  d_in[1];
    const float* dw0 = (const float*)d_in[3];
    const float* db0 = (const float*)d_in[4];
    const float* dw1 = (const float*)d_in[5];
    const float* db1 = (const float*)d_in[6];
    const float* dw2 = (const float*)d_in[7];
    const float* db2 = (const float*)d_in[8];
    const float* gw0 = (const float*)d_in[9];
    const float* gb0 = (const float*)d_in[10];
    const float* gw1 = (const float*)d_in[11];
    const float* gb1 = (const float*)d_in[12];
    const float* gw2 = (const float*)d_in[13];
    const float* gb2 = (const float*)d_in[14];

    float* out = (float*)d_out;
    const int num_dags = (out_size - 8) / 8;
    const int n_nodes  = in_sizes[0] / 13;
    const int npart    = (num_dags + DPP - 1) / DPP;

    // chunk: multiple of 4 (aligned int4 scan + sub-queue key == node&3)
    const int chunk = (((n_nodes + NCHUNK - 1) / NCHUNK) + 3) & ~3;

    const int    nblocks = npart * NCHUNK;
    const size_t p_bytes = (size_t)nblocks * DPP * 8 * sizeof(float);

    if (ws_size >= p_bytes && chunk <= 65535) {
        float* partials = (float*)d_ws;

        // zero only global_summ (dag_summ fully overwritten by K_B)
        hipMemsetAsync(out + (size_t)num_dags * 8, 0, 8 * sizeof(float), stream);

        gsnn_fused2<<<nblocks, NTHR, 0, stream>>>(
            inputs, node_to_dag, dw0, db0, dw1, db1, dw2, db2,
            partials, n_nodes, num_dags, chunk);

        gsnn_dag_finish<<<(num_dags + 255) / 256, 256, 0, stream>>>(
            partials, gw0, gb0, gw1, gb1, gw2, gb2,
            out, out + (size_t)num_dags * 8, num_dags);
    } else {
        // fallback: validated atomic path
        hipMemsetAsync(d_out, 0, (size_t)out_size * sizeof(float), stream);
        gsnn_node_atomic<<<(n_nodes + 255) / 256, 256, 0, stream>>>(
            inputs, node_to_dag, dw0, db0, dw1, db1, dw2, db2, out, n_nodes);
        gsnn_dag_plain<<<(num_dags + 255) / 256, 256, 0, stream>>>(
            out, gw0, gb0, gw1, gb1, gw2, gb2,
            out + (size_t)num_dags * 8, num_dags);
    }
}

// Round 5
// 861.986 us; speedup vs baseline: 1.1483x; 1.1483x over previous
//
#include <hip/hip_runtime.h>

// GraphSNN: per-node MLP (13->16->8->8, relu each layer) -> segment_sum over
// dag ids (20k dags) -> per-dag MLP (8->16->8->8, relu each layer) -> sum.
// Output: [num_dags*8] dag_summ ++ [8] global_summ, fp32.
//
// Round 5: Round-4 structure (validated correct) with the register spill
// fixed: IPT=4 -> IPT=2 (peak live state ~64 floats vs ~200) and
// __launch_bounds__(512,2) so the allocator has a 256-VGPR budget (LDS
// already caps us at 1 block/CU = 2 waves/SIMD, so wide VGPR use is free).
//  - weights staged once in LDS (432 floats), broadcast float4 reads,
//    amortized over 2 nodes in flight per lane
//  - 4 sub-queues keyed by (node & 3): 52B row loads as 4 aligned dwordx4
//  - wave-aggregated queue compaction (1 LDS atomic per wave per slot)
//  - acc rows padded to 9 floats (stride 9 -> conflict-free ds_add)

#define DPP    2880   // dags per partition; acc = 2880*9*4 = 103,680 B
#define NCHUNK 37     // node chunks; 7 partitions * 37 = 259 blocks
#define QC4    2816   // per-sub-queue capacity (exp ~1930, +21 sigma)
#define NTHR   512

// LDS weight layout (float offsets)
#define OW0 0
#define OB0 208
#define OW1 224
#define OB1 352
#define OW2 360
#define OB2 424

// slow path for queue overflow (statistically never taken)
__device__ __forceinline__ void mlp_one_lds(
    const float* __restrict__ inputs, long long n, int drow,
    const float* __restrict__ wl, float* __restrict__ acc)
{
    float x[13];
    #pragma unroll
    for (int k = 0; k < 13; ++k) x[k] = inputs[n * 13 + k];
    float h0[16];
    #pragma unroll
    for (int j = 0; j < 16; ++j) h0[j] = wl[OB0 + j];
    #pragma unroll
    for (int k = 0; k < 13; ++k)
        #pragma unroll
        for (int j = 0; j < 16; ++j) h0[j] = fmaf(x[k], wl[OW0 + k*16 + j], h0[j]);
    #pragma unroll
    for (int j = 0; j < 16; ++j) h0[j] = fmaxf(h0[j], 0.f);
    float h1[8];
    #pragma unroll
    for (int j = 0; j < 8; ++j) h1[j] = wl[OB1 + j];
    #pragma unroll
    for (int k = 0; k < 16; ++k)
        #pragma unroll
        for (int j = 0; j < 8; ++j) h1[j] = fmaf(h0[k], wl[OW1 + k*8 + j], h1[j]);
    #pragma unroll
    for (int j = 0; j < 8; ++j) h1[j] = fmaxf(h1[j], 0.f);
    float h2[8];
    #pragma unroll
    for (int j = 0; j < 8; ++j) h2[j] = wl[OB2 + j];
    #pragma unroll
    for (int k = 0; k < 8; ++k)
        #pragma unroll
        for (int j = 0; j < 8; ++j) h2[j] = fmaf(h1[k], wl[OW2 + k*8 + j], h2[j]);
    float* dst = acc + drow * 9;
    #pragma unroll
    for (int j = 0; j < 8; ++j) atomicAdd(dst + j, fmaxf(h2[j], 0.f));
}

// ---------------------------------------------------------------- K_A
extern "C" __global__ void __launch_bounds__(NTHR, 2) gsnn_fused2(
    const float* __restrict__ inputs,
    const int*   __restrict__ node_to_dag,
    const float* __restrict__ w0, const float* __restrict__ b0,
    const float* __restrict__ w1, const float* __restrict__ b1,
    const float* __restrict__ w2, const float* __restrict__ b2,
    float* __restrict__ partials,      // [npart*NCHUNK][DPP*8]
    int n_nodes, int num_dags, int chunk)
{
    __shared__ float        acc[DPP * 9];       // 103,680 B (stride-9 rows)
    __shared__ unsigned int queue[4][QC4];      // 45,056 B
    __shared__ float        wl[432];            // 1,728 B
    __shared__ int          cnt4[4];

    const int tid = threadIdx.x;
    const int p   = blockIdx.x / NCHUNK;
    const int c   = blockIdx.x % NCHUNK;
    const int lo  = p * DPP;
    const int hi  = min(lo + DPP, num_dags);

    if (tid < 432) {
        float v;
        if      (tid < 208) v = w0[tid];
        else if (tid < 224) v = b0[tid - 208];
        else if (tid < 352) v = w1[tid - 224];
        else if (tid < 360) v = b1[tid - 352];
        else if (tid < 424) v = w2[tid - 360];
        else                v = b2[tid - 424];
        wl[tid] = v;
    }
    for (int i = tid; i < DPP * 9; i += NTHR) acc[i] = 0.f;
    if (tid < 4) cnt4[tid] = 0;
    __syncthreads();

    const int nb   = c * chunk;                 // chunk is a multiple of 4
    const int lane = tid & 63;
    const unsigned long long ltmask = (1ULL << lane) - 1ULL;

    // ---- phase A: scan + 4-way compaction (wave-aggregated atomics) ----
    const int   VC   = chunk >> 2;
    const int4* idx4 = (const int4*)(node_to_dag + nb);
    for (int v = tid; v < VC; v += NTHR) {
        int4 d4;
        const int g = nb + v * 4;
        if (g + 3 < n_nodes) {
            d4 = idx4[v];
        } else {
            d4.x = (g + 0 < n_nodes) ? node_to_dag[g + 0] : -1;
            d4.y = (g + 1 < n_nodes) ? node_to_dag[g + 1] : -1;
            d4.z = (g + 2 < n_nodes) ? node_to_dag[g + 2] : -1;
            d4.w = (g + 3 < n_nodes) ? node_to_dag[g + 3] : -1;
        }
        const int dq[4] = {d4.x, d4.y, d4.z, d4.w};
        #pragma unroll
        for (int q = 0; q < 4; ++q) {
            const int  d    = dq[q];
            const bool pred = (d >= lo) && (d < hi);
            const unsigned long long m = __ballot(pred);
            if (m == 0ULL) continue;
            const int leader = __ffsll((unsigned long long)m) - 1;
            int bpos = 0;
            if (lane == leader) bpos = atomicAdd(&cnt4[q], (int)__popcll(m));
            bpos = __shfl(bpos, leader);
            if (pred) {
                const int pos = bpos + (int)__popcll(m & ltmask);
                const unsigned val =
                    (unsigned)(v * 4 + q) | ((unsigned)(d - lo) << 16);
                if (pos < QC4) queue[q][pos] = val;
                else mlp_one_lds(inputs, (long long)nb + v*4 + q, d - lo, wl, acc);
            }
        }
    }
    __syncthreads();

    // ---- phase B: 2-node-per-lane MLP over each sub-queue (IPT=2) ----
    const float4* w0v = (const float4*)(wl + OW0);
    const float4* b0v = (const float4*)(wl + OB0);
    const float4* w1v = (const float4*)(wl + OW1);
    const float4* b1v = (const float4*)(wl + OB1);
    const float4* w2v = (const float4*)(wl + OW2);
    const float4* b2v = (const float4*)(wl + OB2);
    const float4* in4 = (const float4*)inputs;

    #pragma unroll
    for (int Q = 0; Q < 4; ++Q) {               // Q == (node & 3), compile-time
        const int total = min(cnt4[Q], QC4);
        for (int base = tid * 2; base < total; base += NTHR * 2) {
            const uint2 e2 = *(const uint2*)&queue[Q][base];
            const int   nv = min(total - base, 2);
            unsigned ev[2];
            ev[0] = e2.x;
            ev[1] = (nv > 1) ? e2.y : e2.x;

            float xb[2][16];
            int   drow[2];
            #pragma unroll
            for (int j = 0; j < 2; ++j) {
                const int nloc = (int)(ev[j] & 0xFFFFu);
                drow[j]        = (int)(ev[j] >> 16);
                const long long n = (long long)nb + nloc;   // n & 3 == Q
                if (Q == 3 || n < (long long)n_nodes - 1) {
                    const long long f4 = (n * 13) >> 2;     // 16B-aligned window
                    const float4 r0 = in4[f4 + 0], r1 = in4[f4 + 1];
                    const float4 r2 = in4[f4 + 2], r3 = in4[f4 + 3];
                    xb[j][ 0]=r0.x; xb[j][ 1]=r0.y; xb[j][ 2]=r0.z; xb[j][ 3]=r0.w;
                    xb[j][ 4]=r1.x; xb[j][ 5]=r1.y; xb[j][ 6]=r1.z; xb[j][ 7]=r1.w;
                    xb[j][ 8]=r2.x; xb[j][ 9]=r2.y; xb[j][10]=r2.z; xb[j][11]=r2.w;
                    xb[j][12]=r3.x; xb[j][13]=r3.y; xb[j][14]=r3.z; xb[j][15]=r3.w;
                } else {
                    #pragma unroll
                    for (int k = 0; k < 16; ++k) xb[j][k] = 0.f;
                    #pragma unroll
                    for (int k = 0; k < 13; ++k)
                        xb[j][Q + k] = inputs[n * 13 + k];
                }
            }

            // layer 0: 13 -> 16 (x[k] = xb[.][Q+k], static index)
            float h0[2][16];
            #pragma unroll
            for (int j4 = 0; j4 < 4; ++j4) {
                const float4 bb = b0v[j4];
                #pragma unroll
                for (int j = 0; j < 2; ++j) {
                    h0[j][j4*4+0] = bb.x; h0[j][j4*4+1] = bb.y;
                    h0[j][j4*4+2] = bb.z; h0[j][j4*4+3] = bb.w;
                }
            }
            #pragma unroll
            for (int k = 0; k < 13; ++k) {
                #pragma unroll
                for (int j4 = 0; j4 < 4; ++j4) {
                    const float4 w = w0v[k*4 + j4];
                    #pragma unroll
                    for (int j = 0; j < 2; ++j) {
                        const float xv = xb[j][Q + k];
                        h0[j][j4*4+0] = fmaf(xv, w.x, h0[j][j4*4+0]);
                        h0[j][j4*4+1] = fmaf(xv, w.y, h0[j][j4*4+1]);
                        h0[j][j4*4+2] = fmaf(xv, w.z, h0[j][j4*4+2]);
                        h0[j][j4*4+3] = fmaf(xv, w.w, h0[j][j4*4+3]);
                    }
                }
            }
            #pragma unroll
            for (int j = 0; j < 2; ++j)
                #pragma unroll
                for (int i = 0; i < 16; ++i) h0[j][i] = fmaxf(h0[j][i], 0.f);

            // layer 1: 16 -> 8
            float h1[2][8];
            #pragma unroll
            for (int j4 = 0; j4 < 2; ++j4) {
                const float4 bb = b1v[j4];
                #pragma unroll
                for (int j = 0; j < 2; ++j) {
                    h1[j][j4*4+0] = bb.x; h1[j][j4*4+1] = bb.y;
                    h1[j][j4*4+2] = bb.z; h1[j][j4*4+3] = bb.w;
                }
            }
            #pragma unroll
            for (int k = 0; k < 16; ++k) {
                #pragma unroll
                for (int j4 = 0; j4 < 2; ++j4) {
                    const float4 w = w1v[k*2 + j4];
                    #pragma unroll
                    for (int j = 0; j < 2; ++j) {
                        const float xv = h0[j][k];
                        h1[j][j4*4+0] = fmaf(xv, w.x, h1[j][j4*4+0]);
                        h1[j][j4*4+1] = fmaf(xv, w.y, h1[j][j4*4+1]);
                        h1[j][j4*4+2] = fmaf(xv, w.z, h1[j][j4*4+2]);
                        h1[j][j4*4+3] = fmaf(xv, w.w, h1[j][j4*4+3]);
                    }
                }
            }
            #pragma unroll
            for (int j = 0; j < 2; ++j)
                #pragma unroll
                for (int i = 0; i < 8; ++i) h1[j][i] = fmaxf(h1[j][i], 0.f);

            // layer 2: 8 -> 8
            float h2[2][8];
            #pragma unroll
            for (int j4 = 0; j4 < 2; ++j4) {
                const float4 bb = b2v[j4];
                #pragma unroll
                for (int j = 0; j < 2; ++j) {
                    h2[j][j4*4+0] = bb.x; h2[j][j4*4+1] = bb.y;
                    h2[j][j4*4+2] = bb.z; h2[j][j4*4+3] = bb.w;
                }
            }
            #pragma unroll
            for (int k = 0; k < 8; ++k) {
                #pragma unroll
                for (int j4 = 0; j4 < 2; ++j4) {
                    const float4 w = w2v[k*2 + j4];
                    #pragma unroll
                    for (int j = 0; j < 2; ++j) {
                        const float xv = h1[j][k];
                        h2[j][j4*4+0] = fmaf(xv, w.x, h2[j][j4*4+0]);
                        h2[j][j4*4+1] = fmaf(xv, w.y, h2[j][j4*4+1]);
                        h2[j][j4*4+2] = fmaf(xv, w.z, h2[j][j4*4+2]);
                        h2[j][j4*4+3] = fmaf(xv, w.w, h2[j][j4*4+3]);
                    }
                }
            }

            // scatter: stride-9 rows -> conflict-free ds_add
            #pragma unroll
            for (int j = 0; j < 2; ++j) {
                if (j < nv) {
                    float* dst = acc + drow[j] * 9;
                    #pragma unroll
                    for (int jj = 0; jj < 8; ++jj)
                        atomicAdd(dst + jj, fmaxf(h2[j][jj], 0.f));
                }
            }
        }
    }
    __syncthreads();

    // ---- flush: un-pad stride-9 -> dense [DPP*8] (validated K_B layout) ----
    float4* out4 = (float4*)(partials + (size_t)blockIdx.x * (DPP * 8));
    for (int f = tid; f < DPP * 2; f += NTHR) {
        const int row = f >> 1, j0 = (f & 1) << 2;
        const float* a = acc + row * 9 + j0;
        float4 vv; vv.x = a[0]; vv.y = a[1]; vv.z = a[2]; vv.w = a[3];
        out4[f] = vv;
    }
}

// ---------------------------------------------------------------- K_B
// (round-2/3/4 validated structure)
extern "C" __global__ void __launch_bounds__(256) gsnn_dag_finish(
    const float* __restrict__ partials,
    const float* __restrict__ w0, const float* __restrict__ b0,
    const float* __restrict__ w1, const float* __restrict__ b1,
    const float* __restrict__ w2, const float* __restrict__ b2,
    float* __restrict__ dag_summ,
    float* __restrict__ global_out,
    int num_dags)
{
    __shared__ float4 w0s[32];   // [8][16] as [k*4 + j4]
    __shared__ float4 b0s[4];
    __shared__ float4 w1s[32];   // [16][8] as [k*2 + j4]
    __shared__ float4 b1s[2];
    __shared__ float4 w2s[16];   // [8][8]  as [k*2 + j4]
    __shared__ float4 b2s[2];
    __shared__ float  gsum_s[8];

    const int tid = threadIdx.x;
    {
        float* p;
        p = (float*)w0s; for (int i = tid; i < 128; i += 256) p[i] = w0[i];
        p = (float*)w1s; for (int i = tid; i < 128; i += 256) p[i] = w1[i];
        p = (float*)w2s; if (tid < 64) p[tid] = w2[tid];
        p = (float*)b0s; if (tid < 16) p[tid] = b0[tid];
        p = (float*)b1s; if (tid < 8)  p[tid] = b1[tid];
        p = (float*)b2s; if (tid < 8)  p[tid] = b2[tid];
    }
    if (tid < 8) gsum_s[tid] = 0.f;
    __syncthreads();

    const int d = blockIdx.x * 256 + tid;

    float h2[8] = {0.f,0.f,0.f,0.f,0.f,0.f,0.f,0.f};
    if (d < num_dags) {
        const int p_  = d / DPP;
        const int loc = d - p_ * DPP;
        float x[8] = {0.f,0.f,0.f,0.f,0.f,0.f,0.f,0.f};
        #pragma unroll 4
        for (int cc = 0; cc < NCHUNK; ++cc) {
            const float4* r = (const float4*)(partials +
                ((size_t)(p_ * NCHUNK + cc) * DPP + loc) * 8);
            const float4 a = r[0], b = r[1];
            x[0]+=a.x; x[1]+=a.y; x[2]+=a.z; x[3]+=a.w;
            x[4]+=b.x; x[5]+=b.y; x[6]+=b.z; x[7]+=b.w;
        }
        {   // write dag_summ row
            float4 o0, o1;
            o0.x=x[0]; o0.y=x[1]; o0.z=x[2]; o0.w=x[3];
            o1.x=x[4]; o1.y=x[5]; o1.z=x[6]; o1.w=x[7];
            float4* out4 = (float4*)(dag_summ + (size_t)d * 8);
            out4[0] = o0; out4[1] = o1;
        }

        float h0[16];
        #pragma unroll
        for (int j4 = 0; j4 < 4; ++j4) {
            const float4 b = b0s[j4];
            h0[j4*4+0]=b.x; h0[j4*4+1]=b.y; h0[j4*4+2]=b.z; h0[j4*4+3]=b.w;
        }
        #pragma unroll
        for (int k = 0; k < 8; ++k) {
            #pragma unroll
            for (int j4 = 0; j4 < 4; ++j4) {
                const float4 w = w0s[k*4 + j4];
                h0[j4*4+0] = fmaf(x[k], w.x, h0[j4*4+0]);
                h0[j4*4+1] = fmaf(x[k], w.y, h0[j4*4+1]);
                h0[j4*4+2] = fmaf(x[k], w.z, h0[j4*4+2]);
                h0[j4*4+3] = fmaf(x[k], w.w, h0[j4*4+3]);
            }
        }
        #pragma unroll
        for (int i = 0; i < 16; ++i) h0[i] = fmaxf(h0[i], 0.f);

        float h1[8];
        #pragma unroll
        for (int j4 = 0; j4 < 2; ++j4) {
            const float4 b = b1s[j4];
            h1[j4*4+0]=b.x; h1[j4*4+1]=b.y; h1[j4*4+2]=b.z; h1[j4*4+3]=b.w;
        }
        #pragma unroll
        for (int k = 0; k < 16; ++k) {
            #pragma unroll
            for (int j4 = 0; j4 < 2; ++j4) {
                const float4 w = w1s[k*2 + j4];
                h1[j4*4+0] = fmaf(h0[k], w.x, h1[j4*4+0]);
                h1[j4*4+1] = fmaf(h0[k], w.y, h1[j4*4+1]);
                h1[j4*4+2] = fmaf(h0[k], w.z, h1[j4*4+2]);
                h1[j4*4+3] = fmaf(h0[k], w.w, h1[j4*4+3]);
            }
        }
        #pragma unroll
        for (int i = 0; i < 8; ++i) h1[i] = fmaxf(h1[i], 0.f);

        #pragma unroll
        for (int j4 = 0; j4 < 2; ++j4) {
            const float4 b = b2s[j4];
            h2[j4*4+0]=b.x; h2[j4*4+1]=b.y; h2[j4*4+2]=b.z; h2[j4*4+3]=b.w;
        }
        #pragma unroll
        for (int k = 0; k < 8; ++k) {
            #pragma unroll
            for (int j4 = 0; j4 < 2; ++j4) {
                const float4 w = w2s[k*2 + j4];
                h2[j4*4+0] = fmaf(h1[k], w.x, h2[j4*4+0]);
                h2[j4*4+1] = fmaf(h1[k], w.y, h2[j4*4+1]);
                h2[j4*4+2] = fmaf(h1[k], w.z, h2[j4*4+2]);
                h2[j4*4+3] = fmaf(h1[k], w.w, h2[j4*4+3]);
            }
        }
        #pragma unroll
        for (int i = 0; i < 8; ++i) h2[i] = fmaxf(h2[i], 0.f);
    }

    #pragma unroll
    for (int j = 0; j < 8; ++j) {
        float v = h2[j];
        for (int off = 32; off > 0; off >>= 1) v += __shfl_down(v, off);
        if ((tid & 63) == 0) atomicAdd(&gsum_s[j], v);
    }
    __syncthreads();
    if (tid < 8) atomicAdd(global_out + tid, gsum_s[tid]);
}

// ---------------------------------------------------------------- fallbacks
extern "C" __global__ void __launch_bounds__(256) gsnn_node_atomic(
    const float* __restrict__ inputs,
    const int*   __restrict__ node_to_dag,
    const float* __restrict__ w0, const float* __restrict__ b0,
    const float* __restrict__ w1, const float* __restrict__ b1,
    const float* __restrict__ w2, const float* __restrict__ b2,
    float* __restrict__ dag_out,
    int n_nodes)
{
    const long long i = (long long)blockIdx.x * 256 + threadIdx.x;
    if (i >= n_nodes) return;
    float x[13];
    #pragma unroll
    for (int k = 0; k < 13; ++k) x[k] = inputs[i*13 + k];
    float h0[16];
    #pragma unroll
    for (int j = 0; j < 16; ++j) h0[j] = b0[j];
    #pragma unroll
    for (int k = 0; k < 13; ++k)
        #pragma unroll
        for (int j = 0; j < 16; ++j) h0[j] = fmaf(x[k], w0[k*16+j], h0[j]);
    #pragma unroll
    for (int j = 0; j < 16; ++j) h0[j] = fmaxf(h0[j], 0.f);
    float h1[8];
    #pragma unroll
    for (int j = 0; j < 8; ++j) h1[j] = b1[j];
    #pragma unroll
    for (int k = 0; k < 16; ++k)
        #pragma unroll
        for (int j = 0; j < 8; ++j) h1[j] = fmaf(h0[k], w1[k*8+j], h1[j]);
    #pragma unroll
    for (int j = 0; j < 8; ++j) h1[j] = fmaxf(h1[j], 0.f);
    float h2[8];
    #pragma unroll
    for (int j = 0; j < 8; ++j) h2[j] = b2[j];
    #pragma unroll
    for (int k = 0; k < 8; ++k)
        #pragma unroll
        for (int j = 0; j < 8; ++j) h2[j] = fmaf(h1[k], w2[k*8+j], h2[j]);
    float* dst = dag_out + (long long)node_to_dag[i] * 8;
    #pragma unroll
    for (int j = 0; j < 8; ++j) atomicAdd(dst + j, fmaxf(h2[j], 0.f));
}

extern "C" __global__ void __launch_bounds__(256) gsnn_dag_plain(
    const float* __restrict__ dag_summ,
    const float* __restrict__ w0, const float* __restrict__ b0,
    const float* __restrict__ w1, const float* __restrict__ b1,
    const float* __restrict__ w2, const float* __restrict__ b2,
    float* __restrict__ global_out,
    int num_dags)
{
    __shared__ float gsum_s[8];
    const int tid = threadIdx.x;
    if (tid < 8) gsum_s[tid] = 0.f;
    __syncthreads();
    const int d = blockIdx.x * 256 + tid;
    float h2[8] = {0.f,0.f,0.f,0.f,0.f,0.f,0.f,0.f};
    if (d < num_dags) {
        float x[8];
        #pragma unroll
        for (int j = 0; j < 8; ++j) x[j] = dag_summ[(size_t)d*8 + j];
        float h0[16];
        #pragma unroll
        for (int j = 0; j < 16; ++j) h0[j] = b0[j];
        #pragma unroll
        for (int k = 0; k < 8; ++k)
            #pragma unroll
            for (int j = 0; j < 16; ++j) h0[j] = fmaf(x[k], w0[k*16+j], h0[j]);
        #pragma unroll
        for (int j = 0; j < 16; ++j) h0[j] = fmaxf(h0[j], 0.f);
        float h1[8];
        #pragma unroll
        for (int j = 0; j < 8; ++j) h1[j] = b1[j];
        #pragma unroll
        for (int k = 0; k < 16; ++k)
            #pragma unroll
            for (int j = 0; j < 8; ++j) h1[j] = fmaf(h0[k], w1[k*8+j], h1[j]);
        #pragma unroll
        for (int j = 0; j < 8; ++j) h1[j] = fmaxf(h1[j], 0.f);
        #pragma unroll
        for (int j = 0; j < 8; ++j) h2[j] = b2[j];
        #pragma unroll
        for (int k = 0; k < 8; ++k)
            #pragma unroll
            for (int j = 0; j < 8; ++j) h2[j] = fmaf(h1[k], w2[k*8+j], h2[j]);
        #pragma unroll
        for (int j = 0; j < 8; ++j) h2[j] = fmaxf(h2[j], 0.f);
    }
    #pragma unroll
    for (int j = 0; j < 8; ++j) {
        float v = h2[j];
        for (int off = 32; off > 0; off >>= 1) v += __shfl_down(v, off);
        if ((tid & 63) == 0) atomicAdd(&gsum_s[j], v);
    }
    __syncthreads();
    if (tid < 8) atomicAdd(global_out + tid, gsum_s[tid]);
}

extern "C" void kernel_launch(void* const* d_in, const int* in_sizes, int n_in,
                              void* d_out, int out_size, void* d_ws, size_t ws_size,
                              hipStream_t stream) {
    const float* inputs      = (const float*)d_in[0];
    const int*   node_to_dag = (const int*)  d_in[1];
    const float* dw0 = (const float*)d_in[3];
    const float* db0 = (const float*)d_in[4];
    const float* dw1 = (const float*)d_in[5];
    const float* db1 = (const float*)d_in[6];
    const float* dw2 = (const float*)d_in[7];
    const float* db2 = (const float*)d_in[8];
    const float* gw0 = (const float*)d_in[9];
    const float* gb0 = (const float*)d_in[10];
    const float* gw1 = (const float*)d_in[11];
    const float* gb1 = (const float*)d_in[12];
    const float* gw2 = (const float*)d_in[13];
    const float* gb2 = (const float*)d_in[14];

    float* out = (float*)d_out;
    const int num_dags = (out_size - 8) / 8;
    const int n_nodes  = in_sizes[0] / 13;
    const int npart    = (num_dags + DPP - 1) / DPP;

    // chunk: multiple of 4 (aligned int4 scan + sub-queue key == node&3)
    const int chunk = (((n_nodes + NCHUNK - 1) / NCHUNK) + 3) & ~3;

    const int    nblocks = npart * NCHUNK;
    const size_t p_bytes = (size_t)nblocks * DPP * 8 * sizeof(float);

    if (ws_size >= p_bytes && chunk <= 65535) {
        float* partials = (float*)d_ws;

        // zero only global_summ (dag_summ fully overwritten by K_B)
        hipMemsetAsync(out + (size_t)num_dags * 8, 0, 8 * sizeof(float), stream);

        gsnn_fused2<<<nblocks, NTHR, 0, stream>>>(
            inputs, node_to_dag, dw0, db0, dw1, db1, dw2, db2,
            partials, n_nodes, num_dags, chunk);

        gsnn_dag_finish<<<(num_dags + 255) / 256, 256, 0, stream>>>(
            partials, gw0, gb0, gw1, gb1, gw2, gb2,
            out, out + (size_t)num_dags * 8, num_dags);
    } else {
        // fallback: validated atomic path
        hipMemsetAsync(d_out, 0, (size_t)out_size * sizeof(float), stream);
        gsnn_node_atomic<<<(n_nodes + 255) / 256, 256, 0, stream>>>(
            inputs, node_to_dag, dw0, db0, dw1, db1, dw2, db2, out, n_nodes);
        gsnn_dag_plain<<<(num_dags + 255) / 256, 256, 0, stream>>>(
            out, gw0, gb0, gw1, gb1, gw2, gb2,
            out + (size_t)num_dags * 8, num_dags);
    }
}

// Round 6
// 821.444 us; speedup vs baseline: 1.2050x; 1.0494x over previous
//
#include <hip/hip_runtime.h>

// GraphSNN: per-node MLP (13->16->8->8, relu each layer) -> segment_sum over
// dag ids (20k dags) -> per-dag MLP (8->16->8->8, relu each layer) -> sum.
// Output: [num_dags*8] dag_summ ++ [8] global_summ, fp32.
//
// Round 6: fix the phase-A spill. Rounds 4/5 had WRITE_SIZE ~790 MB of
// scratch traffic INDEPENDENT of phase-B IPT -> the spill came from the
// mlp_one_lds slow path inlined inside the scan/ballot loop (whole-kernel
// regalloc max at that program point). Now:
//   phase A: scan + ballot-compact ONLY; overflow and the (rare) unsafe
//            tail node go to a per-block GLOBAL overflow list (plain store)
//   phase B: branch-free vector MLP, IPT=2, LDS float4 weights
//   phase C: scalar MLP over the overflow list (statistically empty)
//   flush:   stride-9 acc -> dense partials (K_B layout, validated)

#define DPP    2880   // dags per partition; acc = 2880*9*4 = 103,680 B
#define NCHUNK 37     // node chunks; 7 partitions * 37 = 259 blocks
#define QC4    2816   // per-sub-queue capacity (mean ~1946, +21 sigma)
#define NTHR   512

// LDS weight layout (float offsets)
#define OW0 0
#define OB0 208
#define OW1 224
#define OB1 352
#define OW2 360
#define OB2 424

// scalar-path MLP (phase C only; reads weights from LDS)
__device__ __forceinline__ void mlp_one_lds(
    const float* __restrict__ inputs, long long n, int drow,
    const float* __restrict__ wl, float* __restrict__ acc)
{
    float x[13];
    #pragma unroll
    for (int k = 0; k < 13; ++k) x[k] = inputs[n * 13 + k];
    float h0[16];
    #pragma unroll
    for (int j = 0; j < 16; ++j) h0[j] = wl[OB0 + j];
    #pragma unroll
    for (int k = 0; k < 13; ++k)
        #pragma unroll
        for (int j = 0; j < 16; ++j) h0[j] = fmaf(x[k], wl[OW0 + k*16 + j], h0[j]);
    #pragma unroll
    for (int j = 0; j < 16; ++j) h0[j] = fmaxf(h0[j], 0.f);
    float h1[8];
    #pragma unroll
    for (int j = 0; j < 8; ++j) h1[j] = wl[OB1 + j];
    #pragma unroll
    for (int k = 0; k < 16; ++k)
        #pragma unroll
        for (int j = 0; j < 8; ++j) h1[j] = fmaf(h0[k], wl[OW1 + k*8 + j], h1[j]);
    #pragma unroll
    for (int j = 0; j < 8; ++j) h1[j] = fmaxf(h1[j], 0.f);
    float h2[8];
    #pragma unroll
    for (int j = 0; j < 8; ++j) h2[j] = wl[OB2 + j];
    #pragma unroll
    for (int k = 0; k < 8; ++k)
        #pragma unroll
        for (int j = 0; j < 8; ++j) h2[j] = fmaf(h1[k], wl[OW2 + k*8 + j], h2[j]);
    float* dst = acc + drow * 9;
    #pragma unroll
    for (int j = 0; j < 8; ++j) atomicAdd(dst + j, fmaxf(h2[j], 0.f));
}

// ---------------------------------------------------------------- K_A
extern "C" __global__ void __launch_bounds__(NTHR, 2) gsnn_fused3(
    const float* __restrict__ inputs,
    const int*   __restrict__ node_to_dag,
    const float* __restrict__ w0, const float* __restrict__ b0,
    const float* __restrict__ w1, const float* __restrict__ b1,
    const float* __restrict__ w2, const float* __restrict__ b2,
    float*       __restrict__ partials,   // [npart*NCHUNK][DPP*8]
    unsigned int* __restrict__ ovbuf,     // [nblocks][chunk] overflow slots
    int n_nodes, int num_dags, int chunk)
{
    __shared__ float        acc[DPP * 9];       // 103,680 B (stride-9 rows)
    __shared__ unsigned int queue[4][QC4];      // 45,056 B
    __shared__ float        wl[432];            // 1,728 B
    __shared__ int          cnt4[4];
    __shared__ int          ovcnt;

    const int tid = threadIdx.x;
    const int p   = blockIdx.x / NCHUNK;
    const int c   = blockIdx.x % NCHUNK;
    const int lo  = p * DPP;
    const int hi  = min(lo + DPP, num_dags);

    if (tid < 432) {
        float v;
        if      (tid < 208) v = w0[tid];
        else if (tid < 224) v = b0[tid - 208];
        else if (tid < 352) v = w1[tid - 224];
        else if (tid < 360) v = b1[tid - 352];
        else if (tid < 424) v = w2[tid - 360];
        else                v = b2[tid - 424];
        wl[tid] = v;
    }
    for (int i = tid; i < DPP * 9; i += NTHR) acc[i] = 0.f;
    if (tid < 4) cnt4[tid] = 0;
    if (tid == 0) ovcnt = 0;
    __syncthreads();

    const int nb   = c * chunk;                 // chunk is a multiple of 4
    const int lane = tid & 63;
    const unsigned long long ltmask = (1ULL << lane) - 1ULL;
    unsigned int* ovblk = ovbuf + (size_t)blockIdx.x * chunk;

    // ---- phase A: scan + 4-way ballot compaction (NO heavy code here) ----
    const int   VC   = chunk >> 2;
    const int4* idx4 = (const int4*)(node_to_dag + nb);
    for (int v = tid; v < VC; v += NTHR) {
        int4 d4;
        const int g = nb + v * 4;
        if (g + 3 < n_nodes) {
            d4 = idx4[v];
        } else {
            d4.x = (g + 0 < n_nodes) ? node_to_dag[g + 0] : -1;
            d4.y = (g + 1 < n_nodes) ? node_to_dag[g + 1] : -1;
            d4.z = (g + 2 < n_nodes) ? node_to_dag[g + 2] : -1;
            d4.w = (g + 3 < n_nodes) ? node_to_dag[g + 3] : -1;
        }
        const int dq[4] = {d4.x, d4.y, d4.z, d4.w};
        #pragma unroll
        for (int q = 0; q < 4; ++q) {
            const int nloc = v * 4 + q;
            const long long n = (long long)nb + nloc;
            const int  d       = dq[q];
            const bool inrange = (d >= lo) && (d < hi);
            // phase B's 64B vector window is safe unless this is the very
            // last node of the whole array with q != 3
            const bool unsafe  = (n == (long long)n_nodes - 1) && (q != 3);
            const bool pred    = inrange && !unsafe;
            const unsigned val = (unsigned)nloc | ((unsigned)(d - lo) << 16);
            const unsigned long long m = __ballot(pred);
            if (m != 0ULL) {
                const int leader = __ffsll((unsigned long long)m) - 1;
                int bpos = 0;
                if (lane == leader) bpos = atomicAdd(&cnt4[q], (int)__popcll(m));
                bpos = __shfl(bpos, leader);
                if (pred) {
                    const int pos = bpos + (int)__popcll(m & ltmask);
                    if (pos < QC4) queue[q][pos] = val;
                    else { const int op = atomicAdd(&ovcnt, 1); ovblk[op] = val; }
                }
            }
            if (inrange && unsafe) {
                const int op = atomicAdd(&ovcnt, 1); ovblk[op] = val;
            }
        }
    }
    __syncthreads();

    // ---- phase B: branch-free 2-node-per-lane MLP over each sub-queue ----
    const float4* w0v = (const float4*)(wl + OW0);
    const float4* b0v = (const float4*)(wl + OB0);
    const float4* w1v = (const float4*)(wl + OW1);
    const float4* b1v = (const float4*)(wl + OB1);
    const float4* w2v = (const float4*)(wl + OW2);
    const float4* b2v = (const float4*)(wl + OB2);
    const float4* in4 = (const float4*)inputs;

    #pragma unroll
    for (int Q = 0; Q < 4; ++Q) {               // Q == (node & 3), compile-time
        const int total = min(cnt4[Q], QC4);
        for (int base = tid * 2; base < total; base += NTHR * 2) {
            const uint2 e2 = *(const uint2*)&queue[Q][base];
            const int   nv = min(total - base, 2);
            unsigned ev[2];
            ev[0] = e2.x;
            ev[1] = (nv > 1) ? e2.y : e2.x;

            float xb[2][16];
            int   drow[2];
            #pragma unroll
            for (int j = 0; j < 2; ++j) {
                const int nloc = (int)(ev[j] & 0xFFFFu);
                drow[j]        = (int)(ev[j] >> 16);
                const long long n  = (long long)nb + nloc;  // n & 3 == Q
                const long long f4 = (n * 13) >> 2;         // 16B-aligned window
                const float4 r0 = in4[f4 + 0], r1 = in4[f4 + 1];
                const float4 r2 = in4[f4 + 2], r3 = in4[f4 + 3];
                xb[j][ 0]=r0.x; xb[j][ 1]=r0.y; xb[j][ 2]=r0.z; xb[j][ 3]=r0.w;
                xb[j][ 4]=r1.x; xb[j][ 5]=r1.y; xb[j][ 6]=r1.z; xb[j][ 7]=r1.w;
                xb[j][ 8]=r2.x; xb[j][ 9]=r2.y; xb[j][10]=r2.z; xb[j][11]=r2.w;
                xb[j][12]=r3.x; xb[j][13]=r3.y; xb[j][14]=r3.z; xb[j][15]=r3.w;
            }

            // layer 0: 13 -> 16 (x[k] = xb[.][Q+k], static index)
            float h0[2][16];
            #pragma unroll
            for (int j4 = 0; j4 < 4; ++j4) {
                const float4 bb = b0v[j4];
                #pragma unroll
                for (int j = 0; j < 2; ++j) {
                    h0[j][j4*4+0] = bb.x; h0[j][j4*4+1] = bb.y;
                    h0[j][j4*4+2] = bb.z; h0[j][j4*4+3] = bb.w;
                }
            }
            #pragma unroll
            for (int k = 0; k < 13; ++k) {
                #pragma unroll
                for (int j4 = 0; j4 < 4; ++j4) {
                    const float4 w = w0v[k*4 + j4];
                    #pragma unroll
                    for (int j = 0; j < 2; ++j) {
                        const float xv = xb[j][Q + k];
                        h0[j][j4*4+0] = fmaf(xv, w.x, h0[j][j4*4+0]);
                        h0[j][j4*4+1] = fmaf(xv, w.y, h0[j][j4*4+1]);
                        h0[j][j4*4+2] = fmaf(xv, w.z, h0[j][j4*4+2]);
                        h0[j][j4*4+3] = fmaf(xv, w.w, h0[j][j4*4+3]);
                    }
                }
            }
            #pragma unroll
            for (int j = 0; j < 2; ++j)
                #pragma unroll
                for (int i = 0; i < 16; ++i) h0[j][i] = fmaxf(h0[j][i], 0.f);

            // layer 1: 16 -> 8
            float h1[2][8];
            #pragma unroll
            for (int j4 = 0; j4 < 2; ++j4) {
                const float4 bb = b1v[j4];
                #pragma unroll
                for (int j = 0; j < 2; ++j) {
                    h1[j][j4*4+0] = bb.x; h1[j][j4*4+1] = bb.y;
                    h1[j][j4*4+2] = bb.z; h1[j][j4*4+3] = bb.w;
                }
            }
            #pragma unroll
            for (int k = 0; k < 16; ++k) {
                #pragma unroll
                for (int j4 = 0; j4 < 2; ++j4) {
                    const float4 w = w1v[k*2 + j4];
                    #pragma unroll
                    for (int j = 0; j < 2; ++j) {
                        const float xv = h0[j][k];
                        h1[j][j4*4+0] = fmaf(xv, w.x, h1[j][j4*4+0]);
                        h1[j][j4*4+1] = fmaf(xv, w.y, h1[j][j4*4+1]);
                        h1[j][j4*4+2] = fmaf(xv, w.z, h1[j][j4*4+2]);
                        h1[j][j4*4+3] = fmaf(xv, w.w, h1[j][j4*4+3]);
                    }
                }
            }
            #pragma unroll
            for (int j = 0; j < 2; ++j)
                #pragma unroll
                for (int i = 0; i < 8; ++i) h1[j][i] = fmaxf(h1[j][i], 0.f);

            // layer 2: 8 -> 8
            float h2[2][8];
            #pragma unroll
            for (int j4 = 0; j4 < 2; ++j4) {
                const float4 bb = b2v[j4];
                #pragma unroll
                for (int j = 0; j < 2; ++j) {
                    h2[j][j4*4+0] = bb.x; h2[j][j4*4+1] = bb.y;
                    h2[j][j4*4+2] = bb.z; h2[j][j4*4+3] = bb.w;
                }
            }
            #pragma unroll
            for (int k = 0; k < 8; ++k) {
                #pragma unroll
                for (int j4 = 0; j4 < 2; ++j4) {
                    const float4 w = w2v[k*2 + j4];
                    #pragma unroll
                    for (int j = 0; j < 2; ++j) {
                        const float xv = h1[j][k];
                        h2[j][j4*4+0] = fmaf(xv, w.x, h2[j][j4*4+0]);
                        h2[j][j4*4+1] = fmaf(xv, w.y, h2[j][j4*4+1]);
                        h2[j][j4*4+2] = fmaf(xv, w.z, h2[j][j4*4+2]);
                        h2[j][j4*4+3] = fmaf(xv, w.w, h2[j][j4*4+3]);
                    }
                }
            }

            // scatter: stride-9 rows -> conflict-free ds_add
            #pragma unroll
            for (int j = 0; j < 2; ++j) {
                if (j < nv) {
                    float* dst = acc + drow[j] * 9;
                    #pragma unroll
                    for (int jj = 0; jj < 8; ++jj)
                        atomicAdd(dst + jj, fmaxf(h2[j][jj], 0.f));
                }
            }
        }
    }
    __syncthreads();

    // ---- phase C: overflow list (statistically empty; scalar path) ----
    const int ovn = ovcnt;
    for (int i = tid; i < ovn; i += NTHR) {
        const unsigned val = ovblk[i];
        mlp_one_lds(inputs, (long long)nb + (int)(val & 0xFFFFu),
                    (int)(val >> 16), wl, acc);
    }
    if (ovn > 0) __syncthreads();

    // ---- flush: un-pad stride-9 -> dense [DPP*8] (validated K_B layout) ----
    float4* out4 = (float4*)(partials + (size_t)blockIdx.x * (DPP * 8));
    for (int f = tid; f < DPP * 2; f += NTHR) {
        const int row = f >> 1, j0 = (f & 1) << 2;
        const float* a = acc + row * 9 + j0;
        float4 vv; vv.x = a[0]; vv.y = a[1]; vv.z = a[2]; vv.w = a[3];
        out4[f] = vv;
    }
}

// ---------------------------------------------------------------- K_B
// (round-2..5 validated structure)
extern "C" __global__ void __launch_bounds__(256) gsnn_dag_finish(
    const float* __restrict__ partials,
    const float* __restrict__ w0, const float* __restrict__ b0,
    const float* __restrict__ w1, const float* __restrict__ b1,
    const float* __restrict__ w2, const float* __restrict__ b2,
    float* __restrict__ dag_summ,
    float* __restrict__ global_out,
    int num_dags)
{
    __shared__ float4 w0s[32];   // [8][16] as [k*4 + j4]
    __shared__ float4 b0s[4];
    __shared__ float4 w1s[32];   // [16][8] as [k*2 + j4]
    __shared__ float4 b1s[2];
    __shared__ float4 w2s[16];   // [8][8]  as [k*2 + j4]
    __shared__ float4 b2s[2];
    __shared__ float  gsum_s[8];

    const int tid = threadIdx.x;
    {
        float* p;
        p = (float*)w0s; for (int i = tid; i < 128; i += 256) p[i] = w0[i];
        p = (float*)w1s; for (int i = tid; i < 128; i += 256) p[i] = w1[i];
        p = (float*)w2s; if (tid < 64) p[tid] = w2[tid];
        p = (float*)b0s; if (tid < 16) p[tid] = b0[tid];
        p = (float*)b1s; if (tid < 8)  p[tid] = b1[tid];
        p = (float*)b2s; if (tid < 8)  p[tid] = b2[tid];
    }
    if (tid < 8) gsum_s[tid] = 0.f;
    __syncthreads();

    const int d = blockIdx.x * 256 + tid;

    float h2[8] = {0.f,0.f,0.f,0.f,0.f,0.f,0.f,0.f};
    if (d < num_dags) {
        const int p_  = d / DPP;
        const int loc = d - p_ * DPP;
        float x[8] = {0.f,0.f,0.f,0.f,0.f,0.f,0.f,0.f};
        #pragma unroll 4
        for (int cc = 0; cc < NCHUNK; ++cc) {
            const float4* r = (const float4*)(partials +
                ((size_t)(p_ * NCHUNK + cc) * DPP + loc) * 8);
            const float4 a = r[0], b = r[1];
            x[0]+=a.x; x[1]+=a.y; x[2]+=a.z; x[3]+=a.w;
            x[4]+=b.x; x[5]+=b.y; x[6]+=b.z; x[7]+=b.w;
        }
        {   // write dag_summ row
            float4 o0, o1;
            o0.x=x[0]; o0.y=x[1]; o0.z=x[2]; o0.w=x[3];
            o1.x=x[4]; o1.y=x[5]; o1.z=x[6]; o1.w=x[7];
            float4* out4 = (float4*)(dag_summ + (size_t)d * 8);
            out4[0] = o0; out4[1] = o1;
        }

        float h0[16];
        #pragma unroll
        for (int j4 = 0; j4 < 4; ++j4) {
            const float4 b = b0s[j4];
            h0[j4*4+0]=b.x; h0[j4*4+1]=b.y; h0[j4*4+2]=b.z; h0[j4*4+3]=b.w;
        }
        #pragma unroll
        for (int k = 0; k < 8; ++k) {
            #pragma unroll
            for (int j4 = 0; j4 < 4; ++j4) {
                const float4 w = w0s[k*4 + j4];
                h0[j4*4+0] = fmaf(x[k], w.x, h0[j4*4+0]);
                h0[j4*4+1] = fmaf(x[k], w.y, h0[j4*4+1]);
                h0[j4*4+2] = fmaf(x[k], w.z, h0[j4*4+2]);
                h0[j4*4+3] = fmaf(x[k], w.w, h0[j4*4+3]);
            }
        }
        #pragma unroll
        for (int i = 0; i < 16; ++i) h0[i] = fmaxf(h0[i], 0.f);

        float h1[8];
        #pragma unroll
        for (int j4 = 0; j4 < 2; ++j4) {
            const float4 b = b1s[j4];
            h1[j4*4+0]=b.x; h1[j4*4+1]=b.y; h1[j4*4+2]=b.z; h1[j4*4+3]=b.w;
        }
        #pragma unroll
        for (int k = 0; k < 16; ++k) {
            #pragma unroll
            for (int j4 = 0; j4 < 2; ++j4) {
                const float4 w = w1s[k*2 + j4];
                h1[j4*4+0] = fmaf(h0[k], w.x, h1[j4*4+0]);
                h1[j4*4+1] = fmaf(h0[k], w.y, h1[j4*4+1]);
                h1[j4*4+2] = fmaf(h0[k], w.z, h1[j4*4+2]);
                h1[j4*4+3] = fmaf(h0[k], w.w, h1[j4*4+3]);
            }
        }
        #pragma unroll
        for (int i = 0; i < 8; ++i) h1[i] = fmaxf(h1[i], 0.f);

        #pragma unroll
        for (int j4 = 0; j4 < 2; ++j4) {
            const float4 b = b2s[j4];
            h2[j4*4+0]=b.x; h2[j4*4+1]=b.y; h2[j4*4+2]=b.z; h2[j4*4+3]=b.w;
        }
        #pragma unroll
        for (int k = 0; k < 8; ++k) {
            #pragma unroll
            for (int j4 = 0; j4 < 2; ++j4) {
                const float4 w = w2s[k*2 + j4];
                h2[j4*4+0] = fmaf(h1[k], w.x, h2[j4*4+0]);
                h2[j4*4+1] = fmaf(h1[k], w.y, h2[j4*4+1]);
                h2[j4*4+2] = fmaf(h1[k], w.z, h2[j4*4+2]);
                h2[j4*4+3] = fmaf(h1[k], w.w, h2[j4*4+3]);
            }
        }
        #pragma unroll
        for (int i = 0; i < 8; ++i) h2[i] = fmaxf(h2[i], 0.f);
    }

    #pragma unroll
    for (int j = 0; j < 8; ++j) {
        float v = h2[j];
        for (int off = 32; off > 0; off >>= 1) v += __shfl_down(v, off);
        if ((tid & 63) == 0) atomicAdd(&gsum_s[j], v);
    }
    __syncthreads();
    if (tid < 8) atomicAdd(global_out + tid, gsum_s[tid]);
}

// ---------------------------------------------------------------- fallbacks
extern "C" __global__ void __launch_bounds__(256) gsnn_node_atomic(
    const float* __restrict__ inputs,
    const int*   __restrict__ node_to_dag,
    const float* __restrict__ w0, const float* __restrict__ b0,
    const float* __restrict__ w1, const float* __restrict__ b1,
    const float* __restrict__ w2, const float* __restrict__ b2,
    float* __restrict__ dag_out,
    int n_nodes)
{
    const long long i = (long long)blockIdx.x * 256 + threadIdx.x;
    if (i >= n_nodes) return;
    float x[13];
    #pragma unroll
    for (int k = 0; k < 13; ++k) x[k] = inputs[i*13 + k];
    float h0[16];
    #pragma unroll
    for (int j = 0; j < 16; ++j) h0[j] = b0[j];
    #pragma unroll
    for (int k = 0; k < 13; ++k)
        #pragma unroll
        for (int j = 0; j < 16; ++j) h0[j] = fmaf(x[k], w0[k*16+j], h0[j]);
    #pragma unroll
    for (int j = 0; j < 16; ++j) h0[j] = fmaxf(h0[j], 0.f);
    float h1[8];
    #pragma unroll
    for (int j = 0; j < 8; ++j) h1[j] = b1[j];
    #pragma unroll
    for (int k = 0; k < 16; ++k)
        #pragma unroll
        for (int j = 0; j < 8; ++j) h1[j] = fmaf(h0[k], w1[k*8+j], h1[j]);
    #pragma unroll
    for (int j = 0; j < 8; ++j) h1[j] = fmaxf(h1[j], 0.f);
    float h2[8];
    #pragma unroll
    for (int j = 0; j < 8; ++j) h2[j] = b2[j];
    #pragma unroll
    for (int k = 0; k < 8; ++k)
        #pragma unroll
        for (int j = 0; j < 8; ++j) h2[j] = fmaf(h1[k], w2[k*8+j], h2[j]);
    float* dst = dag_out + (long long)node_to_dag[i] * 8;
    #pragma unroll
    for (int j = 0; j < 8; ++j) atomicAdd(dst + j, fmaxf(h2[j], 0.f));
}

extern "C" __global__ void __launch_bounds__(256) gsnn_dag_plain(
    const float* __restrict__ dag_summ,
    const float* __restrict__ w0, const float* __restrict__ b0,
    const float* __restrict__ w1, const float* __restrict__ b1,
    const float* __restrict__ w2, const float* __restrict__ b2,
    float* __restrict__ global_out,
    int num_dags)
{
    __shared__ float gsum_s[8];
    const int tid = threadIdx.x;
    if (tid < 8) gsum_s[tid] = 0.f;
    __syncthreads();
    const int d = blockIdx.x * 256 + tid;
    float h2[8] = {0.f,0.f,0.f,0.f,0.f,0.f,0.f,0.f};
    if (d < num_dags) {
        float x[8];
        #pragma unroll
        for (int j = 0; j < 8; ++j) x[j] = dag_summ[(size_t)d*8 + j];
        float h0[16];
        #pragma unroll
        for (int j = 0; j < 16; ++j) h0[j] = b0[j];
        #pragma unroll
        for (int k = 0; k < 8; ++k)
            #pragma unroll
            for (int j = 0; j < 16; ++j) h0[j] = fmaf(x[k], w0[k*16+j], h0[j]);
        #pragma unroll
        for (int j = 0; j < 16; ++j) h0[j] = fmaxf(h0[j], 0.f);
        float h1[8];
        #pragma unroll
        for (int j = 0; j < 8; ++j) h1[j] = b1[j];
        #pragma unroll
        for (int k = 0; k < 16; ++k)
            #pragma unroll
            for (int j = 0; j < 8; ++j) h1[j] = fmaf(h0[k], w1[k*8+j], h1[j]);
        #pragma unroll
        for (int j = 0; j < 8; ++j) h1[j] = fmaxf(h1[j], 0.f);
        #pragma unroll
        for (int j = 0; j < 8; ++j) h2[j] = b2[j];
        #pragma unroll
        for (int k = 0; k < 8; ++k)
            #pragma unroll
            for (int j = 0; j < 8; ++j) h2[j] = fmaf(h1[k], w2[k*8+j], h2[j]);
        #pragma unroll
        for (int j = 0; j < 8; ++j) h2[j] = fmaxf(h2[j], 0.f);
    }
    #pragma unroll
    for (int j = 0; j < 8; ++j) {
        float v = h2[j];
        for (int off = 32; off > 0; off >>= 1) v += __shfl_down(v, off);
        if ((tid & 63) == 0) atomicAdd(&gsum_s[j], v);
    }
    __syncthreads();
    if (tid < 8) atomicAdd(global_out + tid, gsum_s[tid]);
}

extern "C" void kernel_launch(void* const* d_in, const int* in_sizes, int n_in,
                              void* d_out, int out_size, void* d_ws, size_t ws_size,
                              hipStream_t stream) {
    const float* inputs      = (const float*)d_in[0];
    const int*   node_to_dag = (const int*)  d_in[1];
    const float* dw0 = (const float*)d_in[3];
    const float* db0 = (const float*)d_in[4];
    const float* dw1 = (const float*)d_in[5];
    const float* db1 = (const float*)d_in[6];
    const float* dw2 = (const float*)d_in[7];
    const float* db2 = (const float*)d_in[8];
    const float* gw0 = (const float*)d_in[9];
    const float* gb0 = (const float*)d_in[10];
    const float* gw1 = (const float*)d_in[11];
    const float* gb1 = (const float*)d_in[12];
    const float* gw2 = (const float*)d_in[13];
    const float* gb2 = (const float*)d_in[14];

    float* out = (float*)d_out;
    const int num_dags = (out_size - 8) / 8;
    const int n_nodes  = in_sizes[0] / 13;
    const int npart    = (num_dags + DPP - 1) / DPP;

    // chunk: multiple of 4 (aligned int4 scan + sub-queue key == node&3)
    const int chunk = (((n_nodes + NCHUNK - 1) / NCHUNK) + 3) & ~3;

    const int    nblocks  = npart * NCHUNK;
    const size_t p_bytes  = (size_t)nblocks * DPP * 8 * sizeof(float);
    const size_t ov_bytes = (size_t)nblocks * chunk * sizeof(unsigned int);

    if (ws_size >= p_bytes + ov_bytes && chunk <= 65535) {
        float*        partials = (float*)d_ws;
        unsigned int* ovbuf    = (unsigned int*)((char*)d_ws + p_bytes);

        // zero only global_summ (dag_summ fully overwritten by K_B)
        hipMemsetAsync(out + (size_t)num_dags * 8, 0, 8 * sizeof(float), stream);

        gsnn_fused3<<<nblocks, NTHR, 0, stream>>>(
            inputs, node_to_dag, dw0, db0, dw1, db1, dw2, db2,
            partials, ovbuf, n_nodes, num_dags, chunk);

        gsnn_dag_finish<<<(num_dags + 255) / 256, 256, 0, stream>>>(
            partials, gw0, gb0, gw1, gb1, gw2, gb2,
            out, out + (size_t)num_dags * 8, num_dags);
    } else {
        // fallback: validated atomic path
        hipMemsetAsync(d_out, 0, (size_t)out_size * sizeof(float), stream);
        gsnn_node_atomic<<<(n_nodes + 255) / 256, 256, 0, stream>>>(
            inputs, node_to_dag, dw0, db0, dw1, db1, dw2, db2, out, n_nodes);
        gsnn_dag_plain<<<(num_dags + 255) / 256, 256, 0, stream>>>(
            out, gw0, gb0, gw1, gb1, gw2, gb2,
            out + (size_t)num_dags * 8, num_dags);
    }
}

// Round 7
// 232.952 us; speedup vs baseline: 4.2491x; 3.5262x over previous
//
#include <hip/hip_runtime.h>

// GraphSNN: per-node MLP (13->16->8->8, relu each layer) -> segment_sum over
// dag ids (20k dags) -> per-dag MLP (8->16->8->8, relu each layer) -> sum.
// Output: [num_dags*8] dag_summ ++ [8] global_summ, fp32.
//
// Round 7: back to round-3's proven codegen shape (1 node/thread, flat
// scalar arrays, weights via global-uniform s_load — 52 VGPR, zero scratch)
// — rounds 4-6's IPT-batched register tiles were being placed in scratch
// (~600-790 MB HBM spill traffic, VGPR pinned 128). Retained algorithmic
// wins, all codegen-neutral:
//   - 4 sub-queues keyed by (n & 3): input row loads as 4 aligned dwordx4
//   - wave-aggregated ballot compaction (kills round-3's serialized cnt atomic)
//   - stride-9 LDS accumulator rows (conflict-free ds_add)
//   - overflow/tail -> global list, processed in a separate phase C

#define DPP    2880   // dags per partition; acc = 2880*9*4 = 103,680 B
#define NCHUNK 37     // node chunks; 7 partitions * 37 = 259 blocks
#define QC4    2816   // per-sub-queue capacity (mean ~1946, +21 sigma)
#define NTHR   1024

// scalar MLP, weights from global (uniform -> s_load); used by phase C only
__device__ __forceinline__ void mlp_one(
    const float* __restrict__ inputs, long long n, int drow,
    const float* __restrict__ w0, const float* __restrict__ b0,
    const float* __restrict__ w1, const float* __restrict__ b1,
    const float* __restrict__ w2, const float* __restrict__ b2,
    float* __restrict__ acc)
{
    float x[13];
    #pragma unroll
    for (int k = 0; k < 13; ++k) x[k] = inputs[n * 13 + k];
    float h0[16];
    #pragma unroll
    for (int j = 0; j < 16; ++j) h0[j] = b0[j];
    #pragma unroll
    for (int k = 0; k < 13; ++k)
        #pragma unroll
        for (int j = 0; j < 16; ++j) h0[j] = fmaf(x[k], w0[k*16 + j], h0[j]);
    #pragma unroll
    for (int j = 0; j < 16; ++j) h0[j] = fmaxf(h0[j], 0.f);
    float h1[8];
    #pragma unroll
    for (int j = 0; j < 8; ++j) h1[j] = b1[j];
    #pragma unroll
    for (int k = 0; k < 16; ++k)
        #pragma unroll
        for (int j = 0; j < 8; ++j) h1[j] = fmaf(h0[k], w1[k*8 + j], h1[j]);
    #pragma unroll
    for (int j = 0; j < 8; ++j) h1[j] = fmaxf(h1[j], 0.f);
    float h2[8];
    #pragma unroll
    for (int j = 0; j < 8; ++j) h2[j] = b2[j];
    #pragma unroll
    for (int k = 0; k < 8; ++k)
        #pragma unroll
        for (int j = 0; j < 8; ++j) h2[j] = fmaf(h1[k], w2[k*8 + j], h2[j]);
    float* dst = acc + drow * 9;
    #pragma unroll
    for (int j = 0; j < 8; ++j) atomicAdd(dst + j, fmaxf(h2[j], 0.f));
}

// ---------------------------------------------------------------- K_A
extern "C" __global__ void __launch_bounds__(NTHR) gsnn_fused4(
    const float* __restrict__ inputs,
    const int*   __restrict__ node_to_dag,
    const float* __restrict__ w0, const float* __restrict__ b0,
    const float* __restrict__ w1, const float* __restrict__ b1,
    const float* __restrict__ w2, const float* __restrict__ b2,
    float*        __restrict__ partials,  // [npart*NCHUNK][DPP*8]
    unsigned int* __restrict__ ovbuf,     // [nblocks][chunk] overflow slots
    int n_nodes, int num_dags, int chunk)
{
    __shared__ float        acc[DPP * 9];       // 103,680 B (stride-9 rows)
    __shared__ unsigned int queue[4][QC4];      // 45,056 B
    __shared__ int          cnt4[4];
    __shared__ int          ovcnt;

    const int tid = threadIdx.x;
    const int p   = blockIdx.x / NCHUNK;
    const int c   = blockIdx.x % NCHUNK;
    const int lo  = p * DPP;
    const int hi  = min(lo + DPP, num_dags);

    for (int i = tid; i < DPP * 9; i += NTHR) acc[i] = 0.f;
    if (tid < 4) cnt4[tid] = 0;
    if (tid == 0) ovcnt = 0;
    __syncthreads();

    const int nb   = c * chunk;                 // chunk is a multiple of 4
    const int lane = tid & 63;
    const unsigned long long ltmask = (1ULL << lane) - 1ULL;
    unsigned int* ovblk = ovbuf + (size_t)blockIdx.x * chunk;

    // ---- phase A: scan + 4-way ballot compaction (light code only) ----
    const int   VC   = chunk >> 2;
    const int4* idx4 = (const int4*)(node_to_dag + nb);
    for (int v = tid; v < VC; v += NTHR) {
        int4 d4;
        const int g = nb + v * 4;
        if (g + 3 < n_nodes) {
            d4 = idx4[v];
        } else {
            d4.x = (g + 0 < n_nodes) ? node_to_dag[g + 0] : -1;
            d4.y = (g + 1 < n_nodes) ? node_to_dag[g + 1] : -1;
            d4.z = (g + 2 < n_nodes) ? node_to_dag[g + 2] : -1;
            d4.w = (g + 3 < n_nodes) ? node_to_dag[g + 3] : -1;
        }
        const int dq[4] = {d4.x, d4.y, d4.z, d4.w};
        #pragma unroll
        for (int q = 0; q < 4; ++q) {
            const int nloc = v * 4 + q;
            const long long n = (long long)nb + nloc;
            const int  d       = dq[q];
            const bool inrange = (d >= lo) && (d < hi);
            // phase B reads a 64B aligned window; only the very last node of
            // the whole array with q != 3 could run past the end
            const bool unsafe  = (n == (long long)n_nodes - 1) && (q != 3);
            const bool pred    = inrange && !unsafe;
            const unsigned val = (unsigned)nloc | ((unsigned)(d - lo) << 16);
            const unsigned long long m = __ballot(pred);
            if (m != 0ULL) {
                const int leader = __ffsll((unsigned long long)m) - 1;
                int bpos = 0;
                if (lane == leader) bpos = atomicAdd(&cnt4[q], (int)__popcll(m));
                bpos = __shfl(bpos, leader);
                if (pred) {
                    const int pos = bpos + (int)__popcll(m & ltmask);
                    if (pos < QC4) queue[q][pos] = val;
                    else { const int op = atomicAdd(&ovcnt, 1); ovblk[op] = val; }
                }
            }
            if (inrange && unsafe) {
                const int op = atomicAdd(&ovcnt, 1); ovblk[op] = val;
            }
        }
    }
    __syncthreads();

    // ---- phase B: ONE node per thread, flat arrays (round-3 codegen) ----
    const float4* in4 = (const float4*)inputs;

    #pragma unroll
    for (int Q = 0; Q < 4; ++Q) {               // Q == (node & 3), compile-time
        const int total = min(cnt4[Q], QC4);
        for (int qi = tid; qi < total; qi += NTHR) {
            const unsigned ev   = queue[Q][qi];
            const int      nloc = (int)(ev & 0xFFFFu);
            const int      drow = (int)(ev >> 16);
            const long long n   = (long long)nb + nloc;   // n & 3 == Q
            const long long f4  = (n * 13) >> 2;          // 16B-aligned window

            const float4 r0 = in4[f4 + 0], r1 = in4[f4 + 1];
            const float4 r2 = in4[f4 + 2], r3 = in4[f4 + 3];
            float x[16];
            x[ 0]=r0.x; x[ 1]=r0.y; x[ 2]=r0.z; x[ 3]=r0.w;
            x[ 4]=r1.x; x[ 5]=r1.y; x[ 6]=r1.z; x[ 7]=r1.w;
            x[ 8]=r2.x; x[ 9]=r2.y; x[10]=r2.z; x[11]=r2.w;
            x[12]=r3.x; x[13]=r3.y; x[14]=r3.z; x[15]=r3.w;

            // layer 0: 13 -> 16 (weight reads uniform -> s_load)
            float h0[16];
            #pragma unroll
            for (int j = 0; j < 16; ++j) h0[j] = b0[j];
            #pragma unroll
            for (int k = 0; k < 13; ++k) {
                const float xv = x[Q + k];                // static index
                #pragma unroll
                for (int j = 0; j < 16; ++j)
                    h0[j] = fmaf(xv, w0[k*16 + j], h0[j]);
            }
            #pragma unroll
            for (int j = 0; j < 16; ++j) h0[j] = fmaxf(h0[j], 0.f);

            // layer 1: 16 -> 8
            float h1[8];
            #pragma unroll
            for (int j = 0; j < 8; ++j) h1[j] = b1[j];
            #pragma unroll
            for (int k = 0; k < 16; ++k) {
                #pragma unroll
                for (int j = 0; j < 8; ++j)
                    h1[j] = fmaf(h0[k], w1[k*8 + j], h1[j]);
            }
            #pragma unroll
            for (int j = 0; j < 8; ++j) h1[j] = fmaxf(h1[j], 0.f);

            // layer 2: 8 -> 8
            float h2[8];
            #pragma unroll
            for (int j = 0; j < 8; ++j) h2[j] = b2[j];
            #pragma unroll
            for (int k = 0; k < 8; ++k) {
                #pragma unroll
                for (int j = 0; j < 8; ++j)
                    h2[j] = fmaf(h1[k], w2[k*8 + j], h2[j]);
            }

            // scatter: stride-9 rows -> conflict-free ds_add
            float* dst = acc + drow * 9;
            #pragma unroll
            for (int j = 0; j < 8; ++j)
                atomicAdd(dst + j, fmaxf(h2[j], 0.f));
        }
    }
    __syncthreads();

    // ---- phase C: overflow list (statistically empty) ----
    const int ovn = ovcnt;
    for (int i = tid; i < ovn; i += NTHR) {
        const unsigned val = ovblk[i];
        mlp_one(inputs, (long long)nb + (int)(val & 0xFFFFu),
                (int)(val >> 16), w0, b0, w1, b1, w2, b2, acc);
    }
    if (ovn > 0) __syncthreads();

    // ---- flush: un-pad stride-9 -> dense [DPP*8] (validated K_B layout) ----
    float4* out4 = (float4*)(partials + (size_t)blockIdx.x * (DPP * 8));
    for (int f = tid; f < DPP * 2; f += NTHR) {
        const int row = f >> 1, j0 = (f & 1) << 2;
        const float* a = acc + row * 9 + j0;
        float4 vv; vv.x = a[0]; vv.y = a[1]; vv.z = a[2]; vv.w = a[3];
        out4[f] = vv;
    }
}

// ---------------------------------------------------------------- K_B
// (round-2..6 validated structure)
extern "C" __global__ void __launch_bounds__(256) gsnn_dag_finish(
    const float* __restrict__ partials,
    const float* __restrict__ w0, const float* __restrict__ b0,
    const float* __restrict__ w1, const float* __restrict__ b1,
    const float* __restrict__ w2, const float* __restrict__ b2,
    float* __restrict__ dag_summ,
    float* __restrict__ global_out,
    int num_dags)
{
    __shared__ float4 w0s[32];   // [8][16] as [k*4 + j4]
    __shared__ float4 b0s[4];
    __shared__ float4 w1s[32];   // [16][8] as [k*2 + j4]
    __shared__ float4 b1s[2];
    __shared__ float4 w2s[16];   // [8][8]  as [k*2 + j4]
    __shared__ float4 b2s[2];
    __shared__ float  gsum_s[8];

    const int tid = threadIdx.x;
    {
        float* p;
        p = (float*)w0s; for (int i = tid; i < 128; i += 256) p[i] = w0[i];
        p = (float*)w1s; for (int i = tid; i < 128; i += 256) p[i] = w1[i];
        p = (float*)w2s; if (tid < 64) p[tid] = w2[tid];
        p = (float*)b0s; if (tid < 16) p[tid] = b0[tid];
        p = (float*)b1s; if (tid < 8)  p[tid] = b1[tid];
        p = (float*)b2s; if (tid < 8)  p[tid] = b2[tid];
    }
    if (tid < 8) gsum_s[tid] = 0.f;
    __syncthreads();

    const int d = blockIdx.x * 256 + tid;

    float h2[8] = {0.f,0.f,0.f,0.f,0.f,0.f,0.f,0.f};
    if (d < num_dags) {
        const int p_  = d / DPP;
        const int loc = d - p_ * DPP;
        float x[8] = {0.f,0.f,0.f,0.f,0.f,0.f,0.f,0.f};
        #pragma unroll 4
        for (int cc = 0; cc < NCHUNK; ++cc) {
            const float4* r = (const float4*)(partials +
                ((size_t)(p_ * NCHUNK + cc) * DPP + loc) * 8);
            const float4 a = r[0], b = r[1];
            x[0]+=a.x; x[1]+=a.y; x[2]+=a.z; x[3]+=a.w;
            x[4]+=b.x; x[5]+=b.y; x[6]+=b.z; x[7]+=b.w;
        }
        {   // write dag_summ row
            float4 o0, o1;
            o0.x=x[0]; o0.y=x[1]; o0.z=x[2]; o0.w=x[3];
            o1.x=x[4]; o1.y=x[5]; o1.z=x[6]; o1.w=x[7];
            float4* out4 = (float4*)(dag_summ + (size_t)d * 8);
            out4[0] = o0; out4[1] = o1;
        }

        float h0[16];
        #pragma unroll
        for (int j4 = 0; j4 < 4; ++j4) {
            const float4 b = b0s[j4];
            h0[j4*4+0]=b.x; h0[j4*4+1]=b.y; h0[j4*4+2]=b.z; h0[j4*4+3]=b.w;
        }
        #pragma unroll
        for (int k = 0; k < 8; ++k) {
            #pragma unroll
            for (int j4 = 0; j4 < 4; ++j4) {
                const float4 w = w0s[k*4 + j4];
                h0[j4*4+0] = fmaf(x[k], w.x, h0[j4*4+0]);
                h0[j4*4+1] = fmaf(x[k], w.y, h0[j4*4+1]);
                h0[j4*4+2] = fmaf(x[k], w.z, h0[j4*4+2]);
                h0[j4*4+3] = fmaf(x[k], w.w, h0[j4*4+3]);
            }
        }
        #pragma unroll
        for (int i = 0; i < 16; ++i) h0[i] = fmaxf(h0[i], 0.f);

        float h1[8];
        #pragma unroll
        for (int j4 = 0; j4 < 2; ++j4) {
            const float4 b = b1s[j4];
            h1[j4*4+0]=b.x; h1[j4*4+1]=b.y; h1[j4*4+2]=b.z; h1[j4*4+3]=b.w;
        }
        #pragma unroll
        for (int k = 0; k < 16; ++k) {
            #pragma unroll
            for (int j4 = 0; j4 < 2; ++j4) {
                const float4 w = w1s[k*2 + j4];
                h1[j4*4+0] = fmaf(h0[k], w.x, h1[j4*4+0]);
                h1[j4*4+1] = fmaf(h0[k], w.y, h1[j4*4+1]);
                h1[j4*4+2] = fmaf(h0[k], w.z, h1[j4*4+2]);
                h1[j4*4+3] = fmaf(h0[k], w.w, h1[j4*4+3]);
            }
        }
        #pragma unroll
        for (int i = 0; i < 8; ++i) h1[i] = fmaxf(h1[i], 0.f);

        #pragma unroll
        for (int j4 = 0; j4 < 2; ++j4) {
            const float4 b = b2s[j4];
            h2[j4*4+0]=b.x; h2[j4*4+1]=b.y; h2[j4*4+2]=b.z; h2[j4*4+3]=b.w;
        }
        #pragma unroll
        for (int k = 0; k < 8; ++k) {
            #pragma unroll
            for (int j4 = 0; j4 < 2; ++j4) {
                const float4 w = w2s[k*2 + j4];
                h2[j4*4+0] = fmaf(h1[k], w.x, h2[j4*4+0]);
                h2[j4*4+1] = fmaf(h1[k], w.y, h2[j4*4+1]);
                h2[j4*4+2] = fmaf(h1[k], w.z, h2[j4*4+2]);
                h2[j4*4+3] = fmaf(h1[k], w.w, h2[j4*4+3]);
            }
        }
        #pragma unroll
        for (int i = 0; i < 8; ++i) h2[i] = fmaxf(h2[i], 0.f);
    }

    #pragma unroll
    for (int j = 0; j < 8; ++j) {
        float v = h2[j];
        for (int off = 32; off > 0; off >>= 1) v += __shfl_down(v, off);
        if ((tid & 63) == 0) atomicAdd(&gsum_s[j], v);
    }
    __syncthreads();
    if (tid < 8) atomicAdd(global_out + tid, gsum_s[tid]);
}

// ---------------------------------------------------------------- fallbacks
extern "C" __global__ void __launch_bounds__(256) gsnn_node_atomic(
    const float* __restrict__ inputs,
    const int*   __restrict__ node_to_dag,
    const float* __restrict__ w0, const float* __restrict__ b0,
    const float* __restrict__ w1, const float* __restrict__ b1,
    const float* __restrict__ w2, const float* __restrict__ b2,
    float* __restrict__ dag_out,
    int n_nodes)
{
    const long long i = (long long)blockIdx.x * 256 + threadIdx.x;
    if (i >= n_nodes) return;
    float x[13];
    #pragma unroll
    for (int k = 0; k < 13; ++k) x[k] = inputs[i*13 + k];
    float h0[16];
    #pragma unroll
    for (int j = 0; j < 16; ++j) h0[j] = b0[j];
    #pragma unroll
    for (int k = 0; k < 13; ++k)
        #pragma unroll
        for (int j = 0; j < 16; ++j) h0[j] = fmaf(x[k], w0[k*16+j], h0[j]);
    #pragma unroll
    for (int j = 0; j < 16; ++j) h0[j] = fmaxf(h0[j], 0.f);
    float h1[8];
    #pragma unroll
    for (int j = 0; j < 8; ++j) h1[j] = b1[j];
    #pragma unroll
    for (int k = 0; k < 16; ++k)
        #pragma unroll
        for (int j = 0; j < 8; ++j) h1[j] = fmaf(h0[k], w1[k*8+j], h1[j]);
    #pragma unroll
    for (int j = 0; j < 8; ++j) h1[j] = fmaxf(h1[j], 0.f);
    float h2[8];
    #pragma unroll
    for (int j = 0; j < 8; ++j) h2[j] = b2[j];
    #pragma unroll
    for (int k = 0; k < 8; ++k)
        #pragma unroll
        for (int j = 0; j < 8; ++j) h2[j] = fmaf(h1[k], w2[k*8+j], h2[j]);
    float* dst = dag_out + (long long)node_to_dag[i] * 8;
    #pragma unroll
    for (int j = 0; j < 8; ++j) atomicAdd(dst + j, fmaxf(h2[j], 0.f));
}

extern "C" __global__ void __launch_bounds__(256) gsnn_dag_plain(
    const float* __restrict__ dag_summ,
    const float* __restrict__ w0, const float* __restrict__ b0,
    const float* __restrict__ w1, const float* __restrict__ b1,
    const float* __restrict__ w2, const float* __restrict__ b2,
    float* __restrict__ global_out,
    int num_dags)
{
    __shared__ float gsum_s[8];
    const int tid = threadIdx.x;
    if (tid < 8) gsum_s[tid] = 0.f;
    __syncthreads();
    const int d = blockIdx.x * 256 + tid;
    float h2[8] = {0.f,0.f,0.f,0.f,0.f,0.f,0.f,0.f};
    if (d < num_dags) {
        float x[8];
        #pragma unroll
        for (int j = 0; j < 8; ++j) x[j] = dag_summ[(size_t)d*8 + j];
        float h0[16];
        #pragma unroll
        for (int j = 0; j < 16; ++j) h0[j] = b0[j];
        #pragma unroll
        for (int k = 0; k < 8; ++k)
            #pragma unroll
            for (int j = 0; j < 16; ++j) h0[j] = fmaf(x[k], w0[k*16+j], h0[j]);
        #pragma unroll
        for (int j = 0; j < 16; ++j) h0[j] = fmaxf(h0[j], 0.f);
        float h1[8];
        #pragma unroll
        for (int j = 0; j < 8; ++j) h1[j] = b1[j];
        #pragma unroll
        for (int k = 0; k < 16; ++k)
            #pragma unroll
            for (int j = 0; j < 8; ++j) h1[j] = fmaf(h0[k], w1[k*8+j], h1[j]);
        #pragma unroll
        for (int j = 0; j < 8; ++j) h1[j] = fmaxf(h1[j], 0.f);
        #pragma unroll
        for (int j = 0; j < 8; ++j) h2[j] = b2[j];
        #pragma unroll
        for (int k = 0; k < 8; ++k)
            #pragma unroll
            for (int j = 0; j < 8; ++j) h2[j] = fmaf(h1[k], w2[k*8+j], h2[j]);
        #pragma unroll
        for (int j = 0; j < 8; ++j) h2[j] = fmaxf(h2[j], 0.f);
    }
    #pragma unroll
    for (int j = 0; j < 8; ++j) {
        float v = h2[j];
        for (int off = 32; off > 0; off >>= 1) v += __shfl_down(v, off);
        if ((tid & 63) == 0) atomicAdd(&gsum_s[j], v);
    }
    __syncthreads();
    if (tid < 8) atomicAdd(global_out + tid, gsum_s[tid]);
}

extern "C" void kernel_launch(void* const* d_in, const int* in_sizes, int n_in,
                              void* d_out, int out_size, void* d_ws, size_t ws_size,
                              hipStream_t stream) {
    const float* inputs      = (const float*)d_in[0];
    const int*   node_to_dag = (const int*)  d_in[1];
    const float* dw0 = (const float*)d_in[3];
    const float* db0 = (const float*)d_in[4];
    const float* dw1 = (const float*)d_in[5];
    const float* db1 = (const float*)d_in[6];
    const float* dw2 = (const float*)d_in[7];
    const float* db2 = (const float*)d_in[8];
    const float* gw0 = (const float*)d_in[9];
    const float* gb0 = (const float*)d_in[10];
    const float* gw1 = (const float*)d_in[11];
    const float* gb1 = (const float*)d_in[12];
    const float* gw2 = (const float*)d_in[13];
    const float* gb2 = (const float*)d_in[14];

    float* out = (float*)d_out;
    const int num_dags = (out_size - 8) / 8;
    const int n_nodes  = in_sizes[0] / 13;
    const int npart    = (num_dags + DPP - 1) / DPP;

    // chunk: multiple of 4 (aligned int4 scan + sub-queue key == node&3)
    const int chunk = (((n_nodes + NCHUNK - 1) / NCHUNK) + 3) & ~3;

    const int    nblocks  = npart * NCHUNK;
    const size_t p_bytes  = (size_t)nblocks * DPP * 8 * sizeof(float);
    const size_t ov_bytes = (size_t)nblocks * chunk * sizeof(unsigned int);

    if (ws_size >= p_bytes + ov_bytes && chunk <= 65535) {
        float*        partials = (float*)d_ws;
        unsigned int* ovbuf    = (unsigned int*)((char*)d_ws + p_bytes);

        // zero only global_summ (dag_summ fully overwritten by K_B)
        hipMemsetAsync(out + (size_t)num_dags * 8, 0, 8 * sizeof(float), stream);

        gsnn_fused4<<<nblocks, NTHR, 0, stream>>>(
            inputs, node_to_dag, dw0, db0, dw1, db1, dw2, db2,
            partials, ovbuf, n_nodes, num_dags, chunk);

        gsnn_dag_finish<<<(num_dags + 255) / 256, 256, 0, stream>>>(
            partials, gw0, gb0, gw1, gb1, gw2, gb2,
            out, out + (size_t)num_dags * 8, num_dags);
    } else {
        // fallback: validated atomic path
        hipMemsetAsync(d_out, 0, (size_t)out_size * sizeof(float), stream);
        gsnn_node_atomic<<<(n_nodes + 255) / 256, 256, 0, stream>>>(
            inputs, node_to_dag, dw0, db0, dw1, db1, dw2, db2, out, n_nodes);
        gsnn_dag_plain<<<(num_dags + 255) / 256, 256, 0, stream>>>(
            out, gw0, gb0, gw1, gb1, gw2, gb2,
            out + (size_t)num_dags * 8, num_dags);
    }
}

// Round 8
// 193.829 us; speedup vs baseline: 5.1068x; 1.2018x over previous
//
#include <hip/hip_runtime.h>

// GraphSNN: per-node MLP (13->16->8->8, relu each layer) -> segment_sum over
// dag ids (20k dags) -> per-dag MLP (8->16->8->8, relu each layer) -> sum.
// Output: [num_dags*8] dag_summ ++ [8] global_summ, fp32.
//
// Round 8: round-3's exact kernel shape (single ushort queue, single MLP
// body, 13 scalar x loads, stride-8 acc, inline overflow path — proven
// 52-VGPR spill-free at 130 us) with exactly two changes:
//  1. DPP 4000->2000, NCHUNK 51->52: LDS 149->73 KB -> 2 blocks/CU ->
//     32 waves/CU (2x latency hiding; r7 showed latency-bound: VALU 22%,
//     HBM 10%, occ 29%).
//  2. wave-aggregated ballot for the queue counter (removes ~3.8K
//     serialized same-address LDS atomics per block; r7-validated).

#define DPP    2000   // dags per partition; acc = 2000*8*4 = 64,000 B
#define NCHUNK 52     // node chunks; 10 partitions * 52 = 520 blocks (~2/CU)
#define QCAP   4480   // queue capacity (mean ~3846, sigma ~59 -> +10.7 sigma)
#define NTHR   1024

// per-node MLP + LDS scatter (weights from global: uniform -> s_load)
// — byte-identical math to round 3's validated gsnn_process_node
__device__ __forceinline__ void gsnn_process_node(
    const float* __restrict__ inputs, long long n, int drow,
    const float* __restrict__ w0, const float* __restrict__ b0,
    const float* __restrict__ w1, const float* __restrict__ b1,
    const float* __restrict__ w2, const float* __restrict__ b2,
    float* __restrict__ acc)
{
    const float* xr = inputs + (size_t)n * 13;
    float x[13];
    #pragma unroll
    for (int k = 0; k < 13; ++k) x[k] = xr[k];

    float h0[16];
    #pragma unroll
    for (int j = 0; j < 16; ++j) h0[j] = b0[j];
    #pragma unroll
    for (int k = 0; k < 13; ++k) {
        #pragma unroll
        for (int j = 0; j < 16; ++j) h0[j] = fmaf(x[k], w0[k*16 + j], h0[j]);
    }
    #pragma unroll
    for (int j = 0; j < 16; ++j) h0[j] = fmaxf(h0[j], 0.f);

    float h1[8];
    #pragma unroll
    for (int j = 0; j < 8; ++j) h1[j] = b1[j];
    #pragma unroll
    for (int k = 0; k < 16; ++k) {
        #pragma unroll
        for (int j = 0; j < 8; ++j) h1[j] = fmaf(h0[k], w1[k*8 + j], h1[j]);
    }
    #pragma unroll
    for (int j = 0; j < 8; ++j) h1[j] = fmaxf(h1[j], 0.f);

    float h2[8];
    #pragma unroll
    for (int j = 0; j < 8; ++j) h2[j] = b2[j];
    #pragma unroll
    for (int k = 0; k < 8; ++k) {
        #pragma unroll
        for (int j = 0; j < 8; ++j) h2[j] = fmaf(h1[k], w2[k*8 + j], h2[j]);
    }
    float* dst = acc + (size_t)drow * 8;
    #pragma unroll
    for (int j = 0; j < 8; ++j) atomicAdd(dst + j, fmaxf(h2[j], 0.f));
}

// ---------------------------------------------------------------- K_A
extern "C" __global__ void __launch_bounds__(NTHR) gsnn_fused5(
    const float* __restrict__ inputs,
    const int*   __restrict__ node_to_dag,
    const float* __restrict__ w0, const float* __restrict__ b0,
    const float* __restrict__ w1, const float* __restrict__ b1,
    const float* __restrict__ w2, const float* __restrict__ b2,
    float* __restrict__ partials,      // [npart*NCHUNK][DPP*8]
    int n_nodes, int num_dags, int chunk)
{
    __shared__ float          acc[DPP * 8];   // 64,000 B
    __shared__ unsigned short queue[QCAP];    // 8,960 B
    __shared__ int            cnt;

    const int tid = threadIdx.x;
    const int p   = blockIdx.x / NCHUNK;
    const int c   = blockIdx.x % NCHUNK;
    const int lo  = p * DPP;
    const int hi  = min(lo + DPP, num_dags);

    for (int i = tid; i < DPP * 8; i += NTHR) acc[i] = 0.f;
    if (tid == 0) cnt = 0;
    __syncthreads();

    const int nb   = c * chunk;                 // chunk is a multiple of 4
    const int lane = tid & 63;
    const unsigned long long ltmask = (1ULL << lane) - 1ULL;

    // ---- phase A: scan + wave-aggregated ballot compaction ----
    const int   VC   = chunk >> 2;
    const int4* idx4 = (const int4*)(node_to_dag + nb);
    for (int v = tid; v < VC; v += NTHR) {
        int4 d4;
        const int g = nb + v * 4;
        if (g + 3 < n_nodes) {
            d4 = idx4[v];
        } else {
            d4.x = (g + 0 < n_nodes) ? node_to_dag[g + 0] : -1;
            d4.y = (g + 1 < n_nodes) ? node_to_dag[g + 1] : -1;
            d4.z = (g + 2 < n_nodes) ? node_to_dag[g + 2] : -1;
            d4.w = (g + 3 < n_nodes) ? node_to_dag[g + 3] : -1;
        }
        const int dq[4] = {d4.x, d4.y, d4.z, d4.w};
        #pragma unroll
        for (int q = 0; q < 4; ++q) {
            const int  d    = dq[q];
            const bool pred = (d >= lo) && (d < hi);
            const unsigned long long m = __ballot(pred);
            if (m == 0ULL) continue;
            const int leader = __ffsll((unsigned long long)m) - 1;
            int bpos = 0;
            if (lane == leader) bpos = atomicAdd(&cnt, (int)__popcll(m));
            bpos = __shfl(bpos, leader);
            if (pred) {
                const int pos = bpos + (int)__popcll(m & ltmask);
                if (pos < QCAP) queue[pos] = (unsigned short)(v * 4 + q);
                else gsnn_process_node(inputs, (long long)nb + v*4 + q, d - lo,
                                       w0, b0, w1, b1, w2, b2, acc);
            }
        }
    }
    __syncthreads();

    // ---- phase B: dense MLP over the compacted queue (round-3 codegen) ----
    const int total = min(cnt, QCAP);
    for (int qi = tid; qi < total; qi += NTHR) {
        const int n = nb + (int)queue[qi];
        const int d = node_to_dag[n];          // re-read (L2-warm), saves LDS
        gsnn_process_node(inputs, n, d - lo, w0, b0, w1, b1, w2, b2, acc);
    }
    __syncthreads();

    // ---- flush partial (coalesced float4) ----
    float4*       out4 = (float4*)(partials + (size_t)blockIdx.x * (DPP * 8));
    const float4* a4   = (const float4*)acc;
    for (int i = tid; i < DPP * 2; i += NTHR) out4[i] = a4[i];
}

// ---------------------------------------------------------------- K_B
// (round-2..7 validated structure; DPP/NCHUNK updated)
extern "C" __global__ void __launch_bounds__(256) gsnn_dag_finish(
    const float* __restrict__ partials,
    const float* __restrict__ w0, const float* __restrict__ b0,
    const float* __restrict__ w1, const float* __restrict__ b1,
    const float* __restrict__ w2, const float* __restrict__ b2,
    float* __restrict__ dag_summ,
    float* __restrict__ global_out,
    int num_dags)
{
    __shared__ float4 w0s[32];   // [8][16] as [k*4 + j4]
    __shared__ float4 b0s[4];
    __shared__ float4 w1s[32];   // [16][8] as [k*2 + j4]
    __shared__ float4 b1s[2];
    __shared__ float4 w2s[16];   // [8][8]  as [k*2 + j4]
    __shared__ float4 b2s[2];
    __shared__ float  gsum_s[8];

    const int tid = threadIdx.x;
    {
        float* p;
        p = (float*)w0s; for (int i = tid; i < 128; i += 256) p[i] = w0[i];
        p = (float*)w1s; for (int i = tid; i < 128; i += 256) p[i] = w1[i];
        p = (float*)w2s; if (tid < 64) p[tid] = w2[tid];
        p = (float*)b0s; if (tid < 16) p[tid] = b0[tid];
        p = (float*)b1s; if (tid < 8)  p[tid] = b1[tid];
        p = (float*)b2s; if (tid < 8)  p[tid] = b2[tid];
    }
    if (tid < 8) gsum_s[tid] = 0.f;
    __syncthreads();

    const int d = blockIdx.x * 256 + tid;

    float h2[8] = {0.f,0.f,0.f,0.f,0.f,0.f,0.f,0.f};
    if (d < num_dags) {
        const int p_  = d / DPP;
        const int loc = d - p_ * DPP;
        float x[8] = {0.f,0.f,0.f,0.f,0.f,0.f,0.f,0.f};
        #pragma unroll 4
        for (int cc = 0; cc < NCHUNK; ++cc) {
            const float4* r = (const float4*)(partials +
                ((size_t)(p_ * NCHUNK + cc) * DPP + loc) * 8);
            const float4 a = r[0], b = r[1];
            x[0]+=a.x; x[1]+=a.y; x[2]+=a.z; x[3]+=a.w;
            x[4]+=b.x; x[5]+=b.y; x[6]+=b.z; x[7]+=b.w;
        }
        {   // write dag_summ row
            float4 o0, o1;
            o0.x=x[0]; o0.y=x[1]; o0.z=x[2]; o0.w=x[3];
            o1.x=x[4]; o1.y=x[5]; o1.z=x[6]; o1.w=x[7];
            float4* out4 = (float4*)(dag_summ + (size_t)d * 8);
            out4[0] = o0; out4[1] = o1;
        }

        float h0[16];
        #pragma unroll
        for (int j4 = 0; j4 < 4; ++j4) {
            const float4 b = b0s[j4];
            h0[j4*4+0]=b.x; h0[j4*4+1]=b.y; h0[j4*4+2]=b.z; h0[j4*4+3]=b.w;
        }
        #pragma unroll
        for (int k = 0; k < 8; ++k) {
            #pragma unroll
            for (int j4 = 0; j4 < 4; ++j4) {
                const float4 w = w0s[k*4 + j4];
                h0[j4*4+0] = fmaf(x[k], w.x, h0[j4*4+0]);
                h0[j4*4+1] = fmaf(x[k], w.y, h0[j4*4+1]);
                h0[j4*4+2] = fmaf(x[k], w.z, h0[j4*4+2]);
                h0[j4*4+3] = fmaf(x[k], w.w, h0[j4*4+3]);
            }
        }
        #pragma unroll
        for (int i = 0; i < 16; ++i) h0[i] = fmaxf(h0[i], 0.f);

        float h1[8];
        #pragma unroll
        for (int j4 = 0; j4 < 2; ++j4) {
            const float4 b = b1s[j4];
            h1[j4*4+0]=b.x; h1[j4*4+1]=b.y; h1[j4*4+2]=b.z; h1[j4*4+3]=b.w;
        }
        #pragma unroll
        for (int k = 0; k < 16; ++k) {
            #pragma unroll
            for (int j4 = 0; j4 < 2; ++j4) {
                const float4 w = w1s[k*2 + j4];
                h1[j4*4+0] = fmaf(h0[k], w.x, h1[j4*4+0]);
                h1[j4*4+1] = fmaf(h0[k], w.y, h1[j4*4+1]);
                h1[j4*4+2] = fmaf(h0[k], w.z, h1[j4*4+2]);
                h1[j4*4+3] = fmaf(h0[k], w.w, h1[j4*4+3]);
            }
        }
        #pragma unroll
        for (int i = 0; i < 8; ++i) h1[i] = fmaxf(h1[i], 0.f);

        #pragma unroll
        for (int j4 = 0; j4 < 2; ++j4) {
            const float4 b = b2s[j4];
            h2[j4*4+0]=b.x; h2[j4*4+1]=b.y; h2[j4*4+2]=b.z; h2[j4*4+3]=b.w;
        }
        #pragma unroll
        for (int k = 0; k < 8; ++k) {
            #pragma unroll
            for (int j4 = 0; j4 < 2; ++j4) {
                const float4 w = w2s[k*2 + j4];
                h2[j4*4+0] = fmaf(h1[k], w.x, h2[j4*4+0]);
                h2[j4*4+1] = fmaf(h1[k], w.y, h2[j4*4+1]);
                h2[j4*4+2] = fmaf(h1[k], w.z, h2[j4*4+2]);
                h2[j4*4+3] = fmaf(h1[k], w.w, h2[j4*4+3]);
            }
        }
        #pragma unroll
        for (int i = 0; i < 8; ++i) h2[i] = fmaxf(h2[i], 0.f);
    }

    #pragma unroll
    for (int j = 0; j < 8; ++j) {
        float v = h2[j];
        for (int off = 32; off > 0; off >>= 1) v += __shfl_down(v, off);
        if ((tid & 63) == 0) atomicAdd(&gsum_s[j], v);
    }
    __syncthreads();
    if (tid < 8) atomicAdd(global_out + tid, gsum_s[tid]);
}

// ---------------------------------------------------------------- fallbacks
extern "C" __global__ void __launch_bounds__(256) gsnn_node_atomic(
    const float* __restrict__ inputs,
    const int*   __restrict__ node_to_dag,
    const float* __restrict__ w0, const float* __restrict__ b0,
    const float* __restrict__ w1, const float* __restrict__ b1,
    const float* __restrict__ w2, const float* __restrict__ b2,
    float* __restrict__ dag_out,
    int n_nodes)
{
    const long long i = (long long)blockIdx.x * 256 + threadIdx.x;
    if (i >= n_nodes) return;
    float x[13];
    #pragma unroll
    for (int k = 0; k < 13; ++k) x[k] = inputs[i*13 + k];
    float h0[16];
    #pragma unroll
    for (int j = 0; j < 16; ++j) h0[j] = b0[j];
    #pragma unroll
    for (int k = 0; k < 13; ++k)
        #pragma unroll
        for (int j = 0; j < 16; ++j) h0[j] = fmaf(x[k], w0[k*16+j], h0[j]);
    #pragma unroll
    for (int j = 0; j < 16; ++j) h0[j] = fmaxf(h0[j], 0.f);
    float h1[8];
    #pragma unroll
    for (int j = 0; j < 8; ++j) h1[j] = b1[j];
    #pragma unroll
    for (int k = 0; k < 16; ++k)
        #pragma unroll
        for (int j = 0; j < 8; ++j) h1[j] = fmaf(h0[k], w1[k*8+j], h1[j]);
    #pragma unroll
    for (int j = 0; j < 8; ++j) h1[j] = fmaxf(h1[j], 0.f);
    float h2[8];
    #pragma unroll
    for (int j = 0; j < 8; ++j) h2[j] = b2[j];
    #pragma unroll
    for (int k = 0; k < 8; ++k)
        #pragma unroll
        for (int j = 0; j < 8; ++j) h2[j] = fmaf(h1[k], w2[k*8+j], h2[j]);
    float* dst = dag_out + (long long)node_to_dag[i] * 8;
    #pragma unroll
    for (int j = 0; j < 8; ++j) atomicAdd(dst + j, fmaxf(h2[j], 0.f));
}

extern "C" __global__ void __launch_bounds__(256) gsnn_dag_plain(
    const float* __restrict__ dag_summ,
    const float* __restrict__ w0, const float* __restrict__ b0,
    const float* __restrict__ w1, const float* __restrict__ b1,
    const float* __restrict__ w2, const float* __restrict__ b2,
    float* __restrict__ global_out,
    int num_dags)
{
    __shared__ float gsum_s[8];
    const int tid = threadIdx.x;
    if (tid < 8) gsum_s[tid] = 0.f;
    __syncthreads();
    const int d = blockIdx.x * 256 + tid;
    float h2[8] = {0.f,0.f,0.f,0.f,0.f,0.f,0.f,0.f};
    if (d < num_dags) {
        float x[8];
        #pragma unroll
        for (int j = 0; j < 8; ++j) x[j] = dag_summ[(size_t)d*8 + j];
        float h0[16];
        #pragma unroll
        for (int j = 0; j < 16; ++j) h0[j] = b0[j];
        #pragma unroll
        for (int k = 0; k < 8; ++k)
            #pragma unroll
            for (int j = 0; j < 16; ++j) h0[j] = fmaf(x[k], w0[k*16+j], h0[j]);
        #pragma unroll
        for (int j = 0; j < 16; ++j) h0[j] = fmaxf(h0[j], 0.f);
        float h1[8];
        #pragma unroll
        for (int j = 0; j < 8; ++j) h1[j] = b1[j];
        #pragma unroll
        for (int k = 0; k < 16; ++k)
            #pragma unroll
            for (int j = 0; j < 8; ++j) h1[j] = fmaf(h0[k], w1[k*8+j], h1[j]);
        #pragma unroll
        for (int j = 0; j < 8; ++j) h1[j] = fmaxf(h1[j], 0.f);
        #pragma unroll
        for (int j = 0; j < 8; ++j) h2[j] = b2[j];
        #pragma unroll
        for (int k = 0; k < 8; ++k)
            #pragma unroll
            for (int j = 0; j < 8; ++j) h2[j] = fmaf(h1[k], w2[k*8+j], h2[j]);
        #pragma unroll
        for (int j = 0; j < 8; ++j) h2[j] = fmaxf(h2[j], 0.f);
    }
    #pragma unroll
    for (int j = 0; j < 8; ++j) {
        float v = h2[j];
        for (int off = 32; off > 0; off >>= 1) v += __shfl_down(v, off);
        if ((tid & 63) == 0) atomicAdd(&gsum_s[j], v);
    }
    __syncthreads();
    if (tid < 8) atomicAdd(global_out + tid, gsum_s[tid]);
}

extern "C" void kernel_launch(void* const* d_in, const int* in_sizes, int n_in,
                              void* d_out, int out_size, void* d_ws, size_t ws_size,
                              hipStream_t stream) {
    const float* inputs      = (const float*)d_in[0];
    const int*   node_to_dag = (const int*)  d_in[1];
    const float* dw0 = (const float*)d_in[3];
    const float* db0 = (const float*)d_in[4];
    const float* dw1 = (const float*)d_in[5];
    const float* db1 = (const float*)d_in[6];
    const float* dw2 = (const float*)d_in[7];
    const float* db2 = (const float*)d_in[8];
    const float* gw0 = (const float*)d_in[9];
    const float* gb0 = (const float*)d_in[10];
    const float* gw1 = (const float*)d_in[11];
    const float* gb1 = (const float*)d_in[12];
    const float* gw2 = (const float*)d_in[13];
    const float* gb2 = (const float*)d_in[14];

    float* out = (float*)d_out;
    const int num_dags = (out_size - 8) / 8;
    const int n_nodes  = in_sizes[0] / 13;
    const int npart    = (num_dags + DPP - 1) / DPP;

    // chunk rounded up to a multiple of 4 (aligned int4 scan); must fit ushort
    const int chunk = (((n_nodes + NCHUNK - 1) / NCHUNK) + 3) & ~3;

    const int    nblocks = npart * NCHUNK;
    const size_t p_bytes = (size_t)nblocks * DPP * 8 * sizeof(float);

    if (ws_size >= p_bytes && chunk <= 65535) {
        float* partials = (float*)d_ws;

        // zero only global_summ (dag_summ fully overwritten by K_B)
        hipMemsetAsync(out + (size_t)num_dags * 8, 0, 8 * sizeof(float), stream);

        gsnn_fused5<<<nblocks, NTHR, 0, stream>>>(
            inputs, node_to_dag, dw0, db0, dw1, db1, dw2, db2,
            partials, n_nodes, num_dags, chunk);

        gsnn_dag_finish<<<(num_dags + 255) / 256, 256, 0, stream>>>(
            partials, gw0, gb0, gw1, gb1, gw2, gb2,
            out, out + (size_t)num_dags * 8, num_dags);
    } else {
        // fallback: validated atomic path
        hipMemsetAsync(d_out, 0, (size_t)out_size * sizeof(float), stream);
        gsnn_node_atomic<<<(n_nodes + 255) / 256, 256, 0, stream>>>(
            inputs, node_to_dag, dw0, db0, dw1, db1, dw2, db2, out, n_nodes);
        gsnn_dag_plain<<<(num_dags + 255) / 256, 256, 0, stream>>>(
            out, gw0, gb0, gw1, gb1, gw2, gb2,
            out + (size_t)num_dags * 8, num_dags);
    }
}

// Round 9
// 145.429 us; speedup vs baseline: 6.8064x; 1.3328x over previous
//
#include <hip/hip_runtime.h>

// GraphSNN: per-node MLP (13->16->8->8, relu each layer) -> segment_sum over
// dag ids (20k dags) -> per-dag MLP (8->16->8->8, relu each layer) -> sum.
// Output: [num_dags*8] dag_summ ++ [8] global_summ, fp32.
//
// Round 9: split structure (r2, all kernels individually validated), K1
// rebuilt for coalesced input:
//  K1 gsnn_node_mlp2: 256-node tile staged to LDS with coalesced float4
//     loads (was: 208B-stride per-lane gathers = 64 lines/wave-load, the
//     measured 97us wall). 1 node/thread (the only spill-free shape),
//     LDS float4 weights, 15KB LDS -> 8 blocks/CU -> 32 waves/CU.
//  K2 gsnn_seg_partial: r2's direct-accumulate scan, DPP 5000 (160,000B
//     LDS = the cap) -> only 4 partitions (fewer idx re-scans & s passes).
//  K3 gsnn_dag_finish: validated, geometry updated.

#define TILE   256    // nodes per K1 block
#define DPP    5000   // dags per partition; acc = 5000*8*4 = 160,000 B
#define NCHUNK 64     // node chunks; 4 partitions * 64 = 256 blocks
#define NTHR2  1024

// LDS weight layout (float offsets)
#define OW0 0
#define OB0 208
#define OW1 224
#define OB1 352
#define OW2 360
#define OB2 424

// ---------------------------------------------------------------- K1
extern "C" __global__ void __launch_bounds__(256) gsnn_node_mlp2(
    const float* __restrict__ inputs,
    const float* __restrict__ w0, const float* __restrict__ b0,
    const float* __restrict__ w1, const float* __restrict__ b1,
    const float* __restrict__ w2, const float* __restrict__ b2,
    float* __restrict__ s_out,
    int n_nodes)
{
    __shared__ float xs[TILE * 13];   // 13,312 B
    __shared__ float wl[432];         //  1,728 B

    const int tid = threadIdx.x;

    for (int i = tid; i < 432; i += 256) {
        float v;
        if      (i < 208) v = w0[i];
        else if (i < 224) v = b0[i - 208];
        else if (i < 352) v = w1[i - 224];
        else if (i < 360) v = b1[i - 352];
        else if (i < 424) v = w2[i - 360];
        else              v = b2[i - 424];
        wl[i] = v;
    }

    const long long base   = (long long)blockIdx.x * TILE;
    const int       nvalid = (int)min((long long)TILE, (long long)n_nodes - base);

    // ---- stage tile: fully coalesced ----
    if (nvalid == TILE) {
        // TILE*13 floats = 832 float4; base*13 is 16B-aligned (base % 4 == 0)
        const float4* g4 = (const float4*)(inputs + base * 13);
        float4*       l4 = (float4*)xs;
        #pragma unroll
        for (int j = 0; j < 4; ++j) {
            const int i = tid + j * 256;
            if (i < 832) l4[i] = g4[i];
        }
    } else {
        for (int i = tid; i < nvalid * 13; i += 256)
            xs[i] = inputs[base * 13 + i];
    }
    __syncthreads();

    if (tid >= nvalid) return;

    // x from LDS: lane stride 13 floats (odd) -> conflict-free
    float x[13];
    #pragma unroll
    for (int k = 0; k < 13; ++k) x[k] = xs[tid * 13 + k];

    const float4* w0v = (const float4*)(wl + OW0);
    const float4* b0v = (const float4*)(wl + OB0);
    const float4* w1v = (const float4*)(wl + OW1);
    const float4* b1v = (const float4*)(wl + OB1);
    const float4* w2v = (const float4*)(wl + OW2);
    const float4* b2v = (const float4*)(wl + OB2);

    // layer 0: 13 -> 16
    float h0[16];
    #pragma unroll
    for (int j4 = 0; j4 < 4; ++j4) {
        const float4 b = b0v[j4];
        h0[j4*4+0]=b.x; h0[j4*4+1]=b.y; h0[j4*4+2]=b.z; h0[j4*4+3]=b.w;
    }
    #pragma unroll
    for (int k = 0; k < 13; ++k) {
        const float xv = x[k];
        #pragma unroll
        for (int j4 = 0; j4 < 4; ++j4) {
            const float4 w = w0v[k*4 + j4];
            h0[j4*4+0] = fmaf(xv, w.x, h0[j4*4+0]);
            h0[j4*4+1] = fmaf(xv, w.y, h0[j4*4+1]);
            h0[j4*4+2] = fmaf(xv, w.z, h0[j4*4+2]);
            h0[j4*4+3] = fmaf(xv, w.w, h0[j4*4+3]);
        }
    }
    #pragma unroll
    for (int i = 0; i < 16; ++i) h0[i] = fmaxf(h0[i], 0.f);

    // layer 1: 16 -> 8
    float h1[8];
    #pragma unroll
    for (int j4 = 0; j4 < 2; ++j4) {
        const float4 b = b1v[j4];
        h1[j4*4+0]=b.x; h1[j4*4+1]=b.y; h1[j4*4+2]=b.z; h1[j4*4+3]=b.w;
    }
    #pragma unroll
    for (int k = 0; k < 16; ++k) {
        const float xv = h0[k];
        #pragma unroll
        for (int j4 = 0; j4 < 2; ++j4) {
            const float4 w = w1v[k*2 + j4];
            h1[j4*4+0] = fmaf(xv, w.x, h1[j4*4+0]);
            h1[j4*4+1] = fmaf(xv, w.y, h1[j4*4+1]);
            h1[j4*4+2] = fmaf(xv, w.z, h1[j4*4+2]);
            h1[j4*4+3] = fmaf(xv, w.w, h1[j4*4+3]);
        }
    }
    #pragma unroll
    for (int i = 0; i < 8; ++i) h1[i] = fmaxf(h1[i], 0.f);

    // layer 2: 8 -> 8
    float h2[8];
    #pragma unroll
    for (int j4 = 0; j4 < 2; ++j4) {
        const float4 b = b2v[j4];
        h2[j4*4+0]=b.x; h2[j4*4+1]=b.y; h2[j4*4+2]=b.z; h2[j4*4+3]=b.w;
    }
    #pragma unroll
    for (int k = 0; k < 8; ++k) {
        const float xv = h1[k];
        #pragma unroll
        for (int j4 = 0; j4 < 2; ++j4) {
            const float4 w = w2v[k*2 + j4];
            h2[j4*4+0] = fmaf(xv, w.x, h2[j4*4+0]);
            h2[j4*4+1] = fmaf(xv, w.y, h2[j4*4+1]);
            h2[j4*4+2] = fmaf(xv, w.z, h2[j4*4+2]);
            h2[j4*4+3] = fmaf(xv, w.w, h2[j4*4+3]);
        }
    }

    float4 o0, o1;
    o0.x = fmaxf(h2[0],0.f); o0.y = fmaxf(h2[1],0.f);
    o0.z = fmaxf(h2[2],0.f); o0.w = fmaxf(h2[3],0.f);
    o1.x = fmaxf(h2[4],0.f); o1.y = fmaxf(h2[5],0.f);
    o1.z = fmaxf(h2[6],0.f); o1.w = fmaxf(h2[7],0.f);
    float4* out4 = (float4*)(s_out + (base + tid) * 8);
    out4[0] = o0; out4[1] = o1;
}

// ---------------------------------------------------------------- K2
// r2-validated direct-accumulate scan; DPP 5000 -> 4 partitions
extern "C" __global__ void __launch_bounds__(NTHR2) gsnn_seg_partial(
    const int*   __restrict__ node_to_dag,
    const float* __restrict__ s,
    float*       __restrict__ partials,   // [npart*NCHUNK][DPP*8]
    int n_nodes, int num_dags, int chunk)
{
    __shared__ float acc[DPP * 8];        // 160,000 B

    const int tid = threadIdx.x;
    const int p   = blockIdx.x / NCHUNK;  // dag partition
    const int c   = blockIdx.x % NCHUNK;  // node chunk

    for (int i = tid; i < DPP * 8; i += NTHR2) acc[i] = 0.f;
    __syncthreads();

    const int lo = p * DPP;
    const int hi = min(lo + DPP, num_dags);

    const long long nb = (long long)c * chunk;
    const long long ne = min(nb + (long long)chunk, (long long)n_nodes);

    for (long long i = nb + tid; i < ne; i += NTHR2) {
        const int d = node_to_dag[i];
        if (d >= lo && d < hi) {
            const float4* r = (const float4*)(s + i * 8);
            const float4 a = r[0], b = r[1];
            float* dst = acc + (d - lo) * 8;
            atomicAdd(dst + 0, a.x); atomicAdd(dst + 1, a.y);
            atomicAdd(dst + 2, a.z); atomicAdd(dst + 3, a.w);
            atomicAdd(dst + 4, b.x); atomicAdd(dst + 5, b.y);
            atomicAdd(dst + 6, b.z); atomicAdd(dst + 7, b.w);
        }
    }
    __syncthreads();

    float4*       out4 = (float4*)(partials + (size_t)blockIdx.x * (DPP * 8));
    const float4* a4   = (const float4*)acc;
    for (int i = tid; i < DPP * 2; i += NTHR2) out4[i] = a4[i];
}

// ---------------------------------------------------------------- K3
// (validated structure; DPP/NCHUNK updated)
extern "C" __global__ void __launch_bounds__(256) gsnn_dag_finish(
    const float* __restrict__ partials,
    const float* __restrict__ w0, const float* __restrict__ b0,
    const float* __restrict__ w1, const float* __restrict__ b1,
    const float* __restrict__ w2, const float* __restrict__ b2,
    float* __restrict__ dag_summ,
    float* __restrict__ global_out,
    int num_dags)
{
    __shared__ float4 w0s[32];   // [8][16] as [k*4 + j4]
    __shared__ float4 b0s[4];
    __shared__ float4 w1s[32];   // [16][8] as [k*2 + j4]
    __shared__ float4 b1s[2];
    __shared__ float4 w2s[16];   // [8][8]  as [k*2 + j4]
    __shared__ float4 b2s[2];
    __shared__ float  gsum_s[8];

    const int tid = threadIdx.x;
    {
        float* p;
        p = (float*)w0s; for (int i = tid; i < 128; i += 256) p[i] = w0[i];
        p = (float*)w1s; for (int i = tid; i < 128; i += 256) p[i] = w1[i];
        p = (float*)w2s; if (tid < 64) p[tid] = w2[tid];
        p = (float*)b0s; if (tid < 16) p[tid] = b0[tid];
        p = (float*)b1s; if (tid < 8)  p[tid] = b1[tid];
        p = (float*)b2s; if (tid < 8)  p[tid] = b2[tid];
    }
    if (tid < 8) gsum_s[tid] = 0.f;
    __syncthreads();

    const int d = blockIdx.x * 256 + tid;

    float h2[8] = {0.f,0.f,0.f,0.f,0.f,0.f,0.f,0.f};
    if (d < num_dags) {
        const int p_  = d / DPP;
        const int loc = d - p_ * DPP;
        float x[8] = {0.f,0.f,0.f,0.f,0.f,0.f,0.f,0.f};
        #pragma unroll 4
        for (int cc = 0; cc < NCHUNK; ++cc) {
            const float4* r = (const float4*)(partials +
                ((size_t)(p_ * NCHUNK + cc) * DPP + loc) * 8);
            const float4 a = r[0], b = r[1];
            x[0]+=a.x; x[1]+=a.y; x[2]+=a.z; x[3]+=a.w;
            x[4]+=b.x; x[5]+=b.y; x[6]+=b.z; x[7]+=b.w;
        }
        {   // write dag_summ row
            float4 o0, o1;
            o0.x=x[0]; o0.y=x[1]; o0.z=x[2]; o0.w=x[3];
            o1.x=x[4]; o1.y=x[5]; o1.z=x[6]; o1.w=x[7];
            float4* out4 = (float4*)(dag_summ + (size_t)d * 8);
            out4[0] = o0; out4[1] = o1;
        }

        float h0[16];
        #pragma unroll
        for (int j4 = 0; j4 < 4; ++j4) {
            const float4 b = b0s[j4];
            h0[j4*4+0]=b.x; h0[j4*4+1]=b.y; h0[j4*4+2]=b.z; h0[j4*4+3]=b.w;
        }
        #pragma unroll
        for (int k = 0; k < 8; ++k) {
            #pragma unroll
            for (int j4 = 0; j4 < 4; ++j4) {
                const float4 w = w0s[k*4 + j4];
                h0[j4*4+0] = fmaf(x[k], w.x, h0[j4*4+0]);
                h0[j4*4+1] = fmaf(x[k], w.y, h0[j4*4+1]);
                h0[j4*4+2] = fmaf(x[k], w.z, h0[j4*4+2]);
                h0[j4*4+3] = fmaf(x[k], w.w, h0[j4*4+3]);
            }
        }
        #pragma unroll
        for (int i = 0; i < 16; ++i) h0[i] = fmaxf(h0[i], 0.f);

        float h1[8];
        #pragma unroll
        for (int j4 = 0; j4 < 2; ++j4) {
            const float4 b = b1s[j4];
            h1[j4*4+0]=b.x; h1[j4*4+1]=b.y; h1[j4*4+2]=b.z; h1[j4*4+3]=b.w;
        }
        #pragma unroll
        for (int k = 0; k < 16; ++k) {
            #pragma unroll
            for (int j4 = 0; j4 < 2; ++j4) {
                const float4 w = w1s[k*2 + j4];
                h1[j4*4+0] = fmaf(h0[k], w.x, h1[j4*4+0]);
                h1[j4*4+1] = fmaf(h0[k], w.y, h1[j4*4+1]);
                h1[j4*4+2] = fmaf(h0[k], w.z, h1[j4*4+2]);
                h1[j4*4+3] = fmaf(h0[k], w.w, h1[j4*4+3]);
            }
        }
        #pragma unroll
        for (int i = 0; i < 8; ++i) h1[i] = fmaxf(h1[i], 0.f);

        #pragma unroll
        for (int j4 = 0; j4 < 2; ++j4) {
            const float4 b = b2s[j4];
            h2[j4*4+0]=b.x; h2[j4*4+1]=b.y; h2[j4*4+2]=b.z; h2[j4*4+3]=b.w;
        }
        #pragma unroll
        for (int k = 0; k < 8; ++k) {
            #pragma unroll
            for (int j4 = 0; j4 < 2; ++j4) {
                const float4 w = w2s[k*2 + j4];
                h2[j4*4+0] = fmaf(h1[k], w.x, h2[j4*4+0]);
                h2[j4*4+1] = fmaf(h1[k], w.y, h2[j4*4+1]);
                h2[j4*4+2] = fmaf(h1[k], w.z, h2[j4*4+2]);
                h2[j4*4+3] = fmaf(h1[k], w.w, h2[j4*4+3]);
            }
        }
        #pragma unroll
        for (int i = 0; i < 8; ++i) h2[i] = fmaxf(h2[i], 0.f);
    }

    #pragma unroll
    for (int j = 0; j < 8; ++j) {
        float v = h2[j];
        for (int off = 32; off > 0; off >>= 1) v += __shfl_down(v, off);
        if ((tid & 63) == 0) atomicAdd(&gsum_s[j], v);
    }
    __syncthreads();
    if (tid < 8) atomicAdd(global_out + tid, gsum_s[tid]);
}

// ---------------------------------------------------------------- fallbacks
extern "C" __global__ void __launch_bounds__(256) gsnn_node_atomic(
    const float* __restrict__ inputs,
    const int*   __restrict__ node_to_dag,
    const float* __restrict__ w0, const float* __restrict__ b0,
    const float* __restrict__ w1, const float* __restrict__ b1,
    const float* __restrict__ w2, const float* __restrict__ b2,
    float* __restrict__ dag_out,
    int n_nodes)
{
    const long long i = (long long)blockIdx.x * 256 + threadIdx.x;
    if (i >= n_nodes) return;
    float x[13];
    #pragma unroll
    for (int k = 0; k < 13; ++k) x[k] = inputs[i*13 + k];
    float h0[16];
    #pragma unroll
    for (int j = 0; j < 16; ++j) h0[j] = b0[j];
    #pragma unroll
    for (int k = 0; k < 13; ++k)
        #pragma unroll
        for (int j = 0; j < 16; ++j) h0[j] = fmaf(x[k], w0[k*16+j], h0[j]);
    #pragma unroll
    for (int j = 0; j < 16; ++j) h0[j] = fmaxf(h0[j], 0.f);
    float h1[8];
    #pragma unroll
    for (int j = 0; j < 8; ++j) h1[j] = b1[j];
    #pragma unroll
    for (int k = 0; k < 16; ++k)
        #pragma unroll
        for (int j = 0; j < 8; ++j) h1[j] = fmaf(h0[k], w1[k*8+j], h1[j]);
    #pragma unroll
    for (int j = 0; j < 8; ++j) h1[j] = fmaxf(h1[j], 0.f);
    float h2[8];
    #pragma unroll
    for (int j = 0; j < 8; ++j) h2[j] = b2[j];
    #pragma unroll
    for (int k = 0; k < 8; ++k)
        #pragma unroll
        for (int j = 0; j < 8; ++j) h2[j] = fmaf(h1[k], w2[k*8+j], h2[j]);
    float* dst = dag_out + (long long)node_to_dag[i] * 8;
    #pragma unroll
    for (int j = 0; j < 8; ++j) atomicAdd(dst + j, fmaxf(h2[j], 0.f));
}

extern "C" __global__ void __launch_bounds__(256) gsnn_dag_plain(
    const float* __restrict__ dag_summ,
    const float* __restrict__ w0, const float* __restrict__ b0,
    const float* __restrict__ w1, const float* __restrict__ b1,
    const float* __restrict__ w2, const float* __restrict__ b2,
    float* __restrict__ global_out,
    int num_dags)
{
    __shared__ float gsum_s[8];
    const int tid = threadIdx.x;
    if (tid < 8) gsum_s[tid] = 0.f;
    __syncthreads();
    const int d = blockIdx.x * 256 + tid;
    float h2[8] = {0.f,0.f,0.f,0.f,0.f,0.f,0.f,0.f};
    if (d < num_dags) {
        float x[8];
        #pragma unroll
        for (int j = 0; j < 8; ++j) x[j] = dag_summ[(size_t)d*8 + j];
        float h0[16];
        #pragma unroll
        for (int j = 0; j < 16; ++j) h0[j] = b0[j];
        #pragma unroll
        for (int k = 0; k < 8; ++k)
            #pragma unroll
            for (int j = 0; j < 16; ++j) h0[j] = fmaf(x[k], w0[k*16+j], h0[j]);
        #pragma unroll
        for (int j = 0; j < 16; ++j) h0[j] = fmaxf(h0[j], 0.f);
        float h1[8];
        #pragma unroll
        for (int j = 0; j < 8; ++j) h1[j] = b1[j];
        #pragma unroll
        for (int k = 0; k < 16; ++k)
            #pragma unroll
            for (int j = 0; j < 8; ++j) h1[j] = fmaf(h0[k], w1[k*8+j], h1[j]);
        #pragma unroll
        for (int j = 0; j < 8; ++j) h1[j] = fmaxf(h1[j], 0.f);
        #pragma unroll
        for (int j = 0; j < 8; ++j) h2[j] = b2[j];
        #pragma unroll
        for (int k = 0; k < 8; ++k)
            #pragma unroll
            for (int j = 0; j < 8; ++j) h2[j] = fmaf(h1[k], w2[k*8+j], h2[j]);
        #pragma unroll
        for (int j = 0; j < 8; ++j) h2[j] = fmaxf(h2[j], 0.f);
    }
    #pragma unroll
    for (int j = 0; j < 8; ++j) {
        float v = h2[j];
        for (int off = 32; off > 0; off >>= 1) v += __shfl_down(v, off);
        if ((tid & 63) == 0) atomicAdd(&gsum_s[j], v);
    }
    __syncthreads();
    if (tid < 8) atomicAdd(global_out + tid, gsum_s[tid]);
}

extern "C" void kernel_launch(void* const* d_in, const int* in_sizes, int n_in,
                              void* d_out, int out_size, void* d_ws, size_t ws_size,
                              hipStream_t stream) {
    const float* inputs      = (const float*)d_in[0];
    const int*   node_to_dag = (const int*)  d_in[1];
    const float* dw0 = (const float*)d_in[3];
    const float* db0 = (const float*)d_in[4];
    const float* dw1 = (const float*)d_in[5];
    const float* db1 = (const float*)d_in[6];
    const float* dw2 = (const float*)d_in[7];
    const float* db2 = (const float*)d_in[8];
    const float* gw0 = (const float*)d_in[9];
    const float* gb0 = (const float*)d_in[10];
    const float* gw1 = (const float*)d_in[11];
    const float* gb1 = (const float*)d_in[12];
    const float* gw2 = (const float*)d_in[13];
    const float* gb2 = (const float*)d_in[14];

    float* out = (float*)d_out;
    const int num_dags = (out_size - 8) / 8;
    const int n_nodes  = in_sizes[0] / 13;
    const int npart    = (num_dags + DPP - 1) / DPP;

    // K2 chunk: multiple of 4
    const int chunk = (((n_nodes + NCHUNK - 1) / NCHUNK) + 3) & ~3;

    const int    nblocks2 = npart * NCHUNK;
    const size_t s_bytes  = (size_t)n_nodes * 8 * sizeof(float);
    const size_t p_bytes  = (size_t)nblocks2 * DPP * 8 * sizeof(float);

    if (ws_size >= s_bytes + p_bytes) {
        float* s_ws     = (float*)d_ws;
        float* partials = (float*)((char*)d_ws + s_bytes);

        // zero only global_summ (dag_summ fully overwritten by K3)
        hipMemsetAsync(out + (size_t)num_dags * 8, 0, 8 * sizeof(float), stream);

        const int grid1 = (n_nodes + TILE - 1) / TILE;
        gsnn_node_mlp2<<<grid1, 256, 0, stream>>>(
            inputs, dw0, db0, dw1, db1, dw2, db2, s_ws, n_nodes);

        gsnn_seg_partial<<<nblocks2, NTHR2, 0, stream>>>(
            node_to_dag, s_ws, partials, n_nodes, num_dags, chunk);

        gsnn_dag_finish<<<(num_dags + 255) / 256, 256, 0, stream>>>(
            partials, gw0, gb0, gw1, gb1, gw2, gb2,
            out, out + (size_t)num_dags * 8, num_dags);
    } else {
        // fallback: validated atomic path
        hipMemsetAsync(d_out, 0, (size_t)out_size * sizeof(float), stream);
        gsnn_node_atomic<<<(n_nodes + 255) / 256, 256, 0, stream>>>(
            inputs, node_to_dag, dw0, db0, dw1, db1, dw2, db2, out, n_nodes);
        gsnn_dag_plain<<<(num_dags + 255) / 256, 256, 0, stream>>>(
            out, gw0, gb0, gw1, gb1, gw2, gb2,
            out + (size_t)num_dags * 8, num_dags);
    }
}